// Round 1
// baseline (3588.356 us; speedup 1.0000x reference)
//
#include <hip/hip_runtime.h>
#include <math.h>

#define NPART 64
#define TILE_F 16

__device__ __forceinline__ float relu_(float v){ return fmaxf(v, 0.f); }

// ---------------------------------------------------------------------------
// mesh_conv as GEMM: out[b,f,o] = sum_{k=4c+j} G[b,f,k] * Wt[k,o]
// G built on the fly into LDS from gathered neighbor rows.
// Optional BN-on-load (a*relu(x)+d) and fused relu-stats epilogue.
// ---------------------------------------------------------------------------
template<int CIN,int COUT,bool BN,bool STATS>
__global__ __launch_bounds__(256) void conv_kernel(
    const float* __restrict__ xin, const int* __restrict__ nbr,
    const float* __restrict__ Wt, const float* __restrict__ bn_a,
    const float* __restrict__ bn_d,
    float* __restrict__ out, float* __restrict__ psum, int F)
{
  constexpr int K = 4*CIN;
  constexpr int ROWLEN = K + 4;
  __shared__ float Gs[TILE_F][ROWLEN];
  __shared__ int   nI[TILE_F*3];
  __shared__ float ls[STATS?COUT:1];
  __shared__ float lq[STATS?COUT:1];
  const int t = threadIdx.x;
  const int fbase = blockIdx.x*TILE_F;
  const int b = blockIdx.y;
  const float* __restrict__ xb = xin + (size_t)b*F*CIN;

  if (t < TILE_F*3){ int fi=t/3, j=t-fi*3; int fg=fbase+fi; nI[t]=(fg<F)?nbr[fg*3+j]:0; }
  if (STATS){ for (int i=t;i<COUT;i+=256){ ls[i]=0.f; lq[i]=0.f; } }
  __syncthreads();

  if constexpr (CIN%4==0){
    constexpr int C4=CIN/4;
    for (int idx=t; idx<TILE_F*C4; idx+=256){
      int fi=idx/C4, c4=idx-fi*C4;
      int fg=fbase+fi;
      float* dst=&Gs[fi][16*c4];
      if (fg<F){
        int i1=nI[fi*3], i2=nI[fi*3+1], i3=nI[fi*3+2];
        float4 s =*(const float4*)&xb[(size_t)fg*CIN+4*c4];
        float4 v1=*(const float4*)&xb[(size_t)i1*CIN+4*c4];
        float4 v2=*(const float4*)&xb[(size_t)i2*CIN+4*c4];
        float4 v3=*(const float4*)&xb[(size_t)i3*CIN+4*c4];
        if (BN){
          float4 a4=*(const float4*)&bn_a[4*c4];
          float4 d4=*(const float4*)&bn_d[4*c4];
          s.x =fmaf(relu_(s.x ),a4.x,d4.x); s.y =fmaf(relu_(s.y ),a4.y,d4.y);
          s.z =fmaf(relu_(s.z ),a4.z,d4.z); s.w =fmaf(relu_(s.w ),a4.w,d4.w);
          v1.x=fmaf(relu_(v1.x),a4.x,d4.x); v1.y=fmaf(relu_(v1.y),a4.y,d4.y);
          v1.z=fmaf(relu_(v1.z),a4.z,d4.z); v1.w=fmaf(relu_(v1.w),a4.w,d4.w);
          v2.x=fmaf(relu_(v2.x),a4.x,d4.x); v2.y=fmaf(relu_(v2.y),a4.y,d4.y);
          v2.z=fmaf(relu_(v2.z),a4.z,d4.z); v2.w=fmaf(relu_(v2.w),a4.w,d4.w);
          v3.x=fmaf(relu_(v3.x),a4.x,d4.x); v3.y=fmaf(relu_(v3.y),a4.y,d4.y);
          v3.z=fmaf(relu_(v3.z),a4.z,d4.z); v3.w=fmaf(relu_(v3.w),a4.w,d4.w);
        }
        #define FEAT(cc,sv,av,bv,cv) { dst[4*cc+0]=sv; dst[4*cc+1]=av+bv+cv; \
          dst[4*cc+2]=fabsf(av-bv)+fabsf(bv-cv)+fabsf(cv-av); \
          dst[4*cc+3]=fmaxf(fmaxf(av,bv),cv); }
        FEAT(0,s.x,v1.x,v2.x,v3.x)
        FEAT(1,s.y,v1.y,v2.y,v3.y)
        FEAT(2,s.z,v1.z,v2.z,v3.z)
        FEAT(3,s.w,v1.w,v2.w,v3.w)
        #undef FEAT
      } else {
        #pragma unroll
        for (int q=0;q<16;q++) dst[q]=0.f;
      }
    }
  } else {
    for (int idx=t; idx<TILE_F*CIN; idx+=256){
      int fi=idx/CIN, c=idx-fi*CIN;
      int fg=fbase+fi;
      float* dst=&Gs[fi][4*c];
      if (fg<F){
        int i1=nI[fi*3], i2=nI[fi*3+1], i3=nI[fi*3+2];
        float s =xb[(size_t)fg*CIN+c];
        float v1=xb[(size_t)i1*CIN+c];
        float v2=xb[(size_t)i2*CIN+c];
        float v3=xb[(size_t)i3*CIN+c];
        if (BN){ float a=bn_a[c], dd=bn_d[c];
          s=fmaf(relu_(s),a,dd); v1=fmaf(relu_(v1),a,dd);
          v2=fmaf(relu_(v2),a,dd); v3=fmaf(relu_(v3),a,dd); }
        dst[0]=s; dst[1]=v1+v2+v3;
        dst[2]=fabsf(v1-v2)+fabsf(v2-v3)+fabsf(v3-v1);
        dst[3]=fmaxf(fmaxf(v1,v2),v3);
      } else { dst[0]=0.f;dst[1]=0.f;dst[2]=0.f;dst[3]=0.f; }
    }
  }
  __syncthreads();

  constexpr int OQ=COUT/4;
  constexpr int R=256/OQ;
  constexpr int FPT=TILE_F/R;
  const int col=t%OQ, row=t/OQ;
  const int o0=col*4, f0=row*FPT;
  float4 acc[FPT];
  #pragma unroll
  for (int fi=0;fi<FPT;fi++){ acc[fi].x=0.f;acc[fi].y=0.f;acc[fi].z=0.f;acc[fi].w=0.f; }

  for (int k=0;k<K;k+=4){
    float4 w0=*(const float4*)&Wt[(size_t)(k+0)*COUT+o0];
    float4 w1=*(const float4*)&Wt[(size_t)(k+1)*COUT+o0];
    float4 w2=*(const float4*)&Wt[(size_t)(k+2)*COUT+o0];
    float4 w3=*(const float4*)&Wt[(size_t)(k+3)*COUT+o0];
    #pragma unroll
    for (int fi=0;fi<FPT;fi++){
      float4 g=*(const float4*)&Gs[f0+fi][k];
      acc[fi].x=fmaf(g.x,w0.x,fmaf(g.y,w1.x,fmaf(g.z,w2.x,fmaf(g.w,w3.x,acc[fi].x))));
      acc[fi].y=fmaf(g.x,w0.y,fmaf(g.y,w1.y,fmaf(g.z,w2.y,fmaf(g.w,w3.y,acc[fi].y))));
      acc[fi].z=fmaf(g.x,w0.z,fmaf(g.y,w1.z,fmaf(g.z,w2.z,fmaf(g.w,w3.z,acc[fi].z))));
      acc[fi].w=fmaf(g.x,w0.w,fmaf(g.y,w1.w,fmaf(g.z,w2.w,fmaf(g.w,w3.w,acc[fi].w))));
    }
  }

  float4 rs={0,0,0,0}, rq={0,0,0,0};
  #pragma unroll
  for (int fi=0;fi<FPT;fi++){
    int fg=fbase+f0+fi;
    if (fg<F){
      *(float4*)&out[((size_t)b*F+fg)*COUT+o0]=acc[fi];
      if (STATS){
        float rx=relu_(acc[fi].x), ry=relu_(acc[fi].y);
        float rz=relu_(acc[fi].z), rw=relu_(acc[fi].w);
        rs.x+=rx; rs.y+=ry; rs.z+=rz; rs.w+=rw;
        rq.x+=rx*rx; rq.y+=ry*ry; rq.z+=rz*rz; rq.w+=rw*rw;
      }
    }
  }
  if (STATS){
    atomicAdd(&ls[o0+0],rs.x); atomicAdd(&ls[o0+1],rs.y);
    atomicAdd(&ls[o0+2],rs.z); atomicAdd(&ls[o0+3],rs.w);
    atomicAdd(&lq[o0+0],rq.x); atomicAdd(&lq[o0+1],rq.y);
    atomicAdd(&lq[o0+2],rq.z); atomicAdd(&lq[o0+3],rq.w);
    __syncthreads();
    int part=(blockIdx.y*gridDim.x+blockIdx.x)&(NPART-1);
    for (int i=t;i<COUT;i+=256){
      atomicAdd(&psum[(size_t)part*256+i], ls[i]);
      atomicAdd(&psum[(size_t)(NPART+part)*256+i], lq[i]);
    }
  }
}

// psum rows 0..63 = partial sums, rows 64..127 = partial sumsq (stride 256)
__global__ __launch_bounds__(256) void finalize_kernel(
    const float* __restrict__ psum, const float* __restrict__ g,
    const float* __restrict__ bb, float* __restrict__ a, float* __restrict__ d,
    int C, float invN)
{
  int c=threadIdx.x;
  if (c<C){
    float s=0.f,q=0.f;
    for (int p=0;p<NPART;p++){ s+=psum[(size_t)p*256+c]; q+=psum[(size_t)(NPART+p)*256+c]; }
    float m=s*invN, v=q*invN-m*m;
    float ai=g[c]*rsqrtf(v+1e-5f);
    a[c]=ai; d[c]=bb[c]-m*ai;
  }
}

// z = relu(y0 + y3) in-place into y3 buffer, with per-channel sum/sumsq stats
template<int C>
__global__ __launch_bounds__(256) void add_relu_stats_kernel(
    const float* __restrict__ y0, float* __restrict__ z,
    float* __restrict__ psum, int n4)
{
  __shared__ float ls[C], lq[C];
  for (int i=threadIdx.x;i<C;i+=256){ ls[i]=0.f; lq[i]=0.f; }
  __syncthreads();
  int i0=blockIdx.x*256+threadIdx.x;
  int stride=gridDim.x*256;
  int c0=(i0*4)%C;   // stride*4 is a multiple of C, so c0 is loop-invariant
  float4 rs={0,0,0,0}, rq={0,0,0,0};
  for (int i=i0;i<n4;i+=stride){
    float4 a=*(const float4*)&y0[(size_t)i*4];
    float4 bq=*(const float4*)&z[(size_t)i*4];
    float4 v;
    v.x=relu_(a.x+bq.x); v.y=relu_(a.y+bq.y);
    v.z=relu_(a.z+bq.z); v.w=relu_(a.w+bq.w);
    *(float4*)&z[(size_t)i*4]=v;
    rs.x+=v.x; rs.y+=v.y; rs.z+=v.z; rs.w+=v.w;
    rq.x+=v.x*v.x; rq.y+=v.y*v.y; rq.z+=v.z*v.z; rq.w+=v.w*v.w;
  }
  atomicAdd(&ls[c0+0],rs.x); atomicAdd(&ls[c0+1],rs.y);
  atomicAdd(&ls[c0+2],rs.z); atomicAdd(&ls[c0+3],rs.w);
  atomicAdd(&lq[c0+0],rq.x); atomicAdd(&lq[c0+1],rq.y);
  atomicAdd(&lq[c0+2],rq.z); atomicAdd(&lq[c0+3],rq.w);
  __syncthreads();
  int part=blockIdx.x&(NPART-1);
  for (int i=threadIdx.x;i<C;i+=256){
    atomicAdd(&psum[(size_t)part*256+i],ls[i]);
    atomicAdd(&psum[(size_t)(NPART+part)*256+i],lq[i]);
  }
}

// out[b,p,c] = mean_k relu(a[c]*z[b,pool[p,k],c]+d[c])
__global__ __launch_bounds__(256) void pool_kernel(
    const float* __restrict__ z, const int* __restrict__ pl,
    const float* __restrict__ a, const float* __restrict__ d,
    float* __restrict__ out, int C4, int F, int Fn, int n4)
{
  const int C=C4*4;
  for (int i=blockIdx.x*256+threadIdx.x; i<n4; i+=gridDim.x*256){
    int c4=i%C4; int rest=i/C4; int p=rest%Fn; int b=rest/Fn;
    int p0=pl[p*3], p1=pl[p*3+1], p2=pl[p*3+2];
    float4 a4=*(const float4*)&a[4*c4], d4=*(const float4*)&d[4*c4];
    float4 v0=*(const float4*)&z[((size_t)b*F+p0)*C+4*c4];
    float4 v1=*(const float4*)&z[((size_t)b*F+p1)*C+4*c4];
    float4 v2=*(const float4*)&z[((size_t)b*F+p2)*C+4*c4];
    float4 r;
    r.x=(relu_(fmaf(v0.x,a4.x,d4.x))+relu_(fmaf(v1.x,a4.x,d4.x))+relu_(fmaf(v2.x,a4.x,d4.x)))*(1.f/3.f);
    r.y=(relu_(fmaf(v0.y,a4.y,d4.y))+relu_(fmaf(v1.y,a4.y,d4.y))+relu_(fmaf(v2.y,a4.y,d4.y)))*(1.f/3.f);
    r.z=(relu_(fmaf(v0.z,a4.z,d4.z))+relu_(fmaf(v1.z,a4.z,d4.z))+relu_(fmaf(v2.z,a4.z,d4.z)))*(1.f/3.f);
    r.w=(relu_(fmaf(v0.w,a4.w,d4.w))+relu_(fmaf(v1.w,a4.w,d4.w))+relu_(fmaf(v2.w,a4.w,d4.w)))*(1.f/3.f);
    *(float4*)&out[((size_t)b*Fn+p)*C+4*c4]=r;
  }
}

// per-(b,c) column sum over f (C fixed at 256)
__global__ __launch_bounds__(256) void colsum_kernel(
    const float* __restrict__ x, float* __restrict__ bc, int F, int chunk)
{
  int b=blockIdx.y; int f0=blockIdx.x*chunk;
  int c=threadIdx.x;
  int fe=f0+chunk; if (fe>F) fe=F;
  float s=0.f;
  for (int f=f0;f<fe;f++) s+=x[((size_t)b*F+f)*256+c];
  atomicAdd(&bc[b*256+c], s);
}

__global__ __launch_bounds__(256) void head_kernel(
    const float* __restrict__ bc, const float* __restrict__ w1,
    const float* __restrict__ b1, const float* __restrict__ w2,
    const float* __restrict__ b2, float* __restrict__ outp, float invF)
{
  __shared__ float xm[8*256];
  __shared__ float h[8*128];
  int t=threadIdx.x;
  for (int i=t;i<2048;i+=256) xm[i]=bc[i]*invF;
  __syncthreads();
  #pragma unroll
  for (int r=0;r<4;r++){
    int idx=t+r*256; int b=idx>>7, j=idx&127;
    float s=b1[j];
    for (int c=0;c<256;c++) s=fmaf(xm[b*256+c],w1[j*256+c],s);
    h[idx]=relu_(s);
  }
  __syncthreads();
  if (t<8){
    float s=b2[0];
    for (int j=0;j<128;j++) s=fmaf(h[t*128+j],w2[j],s);
    outp[t]=1.f/(1.f+expf(-s));
  }
}

__global__ __launch_bounds__(256) void transpose_in_kernel(
    const float* __restrict__ x, float* __restrict__ xt, int F)
{
  int i=blockIdx.x*256+threadIdx.x;
  int total=8*9*F;
  if (i<total){ int f=i%F; int c=(i/F)%9; int b=i/(9*F);
    xt[((size_t)b*F+f)*9+c]=x[i]; }
}

__global__ __launch_bounds__(256) void transpose_w_kernel(
    const float* __restrict__ w, float* __restrict__ wt, int K, int COUT)
{
  int i=blockIdx.x*256+threadIdx.x;
  if (i<K*COUT){ int o=i/K, k=i-o*K; wt[(size_t)k*COUT+o]=w[i]; }
}

// ---------------------------------------------------------------------------

template<int CIN,int COUT,bool BN,bool STATS>
static void launch_conv(const float* xin, const int* nbr, const float* Wt,
                        const float* a, const float* d, float* out,
                        float* psum, int F, hipStream_t stream)
{
  dim3 grid((F+TILE_F-1)/TILE_F, 8);
  conv_kernel<CIN,COUT,BN,STATS><<<grid,256,0,stream>>>(xin,nbr,Wt,a,d,out,psum,F);
}

extern "C" void kernel_launch(void* const* d_in, const int* in_sizes, int n_in,
                              void* d_out, int out_size, void* d_ws, size_t ws_size,
                              hipStream_t stream)
{
  const float* x    =(const float*)d_in[0];
  const int*  nbr0  =(const int*)d_in[1];
  const int*  pool0 =(const int*)d_in[2];
  const int*  nbr1  =(const int*)d_in[3];
  const int*  pool1 =(const int*)d_in[4];
  const int*  nbr2  =(const int*)d_in[5];
  const int*  pool2 =(const int*)d_in[6];
  const float* wc0  =(const float*)d_in[7];
  const float* ws0  =(const float*)d_in[8];
  const float* bng0 =(const float*)d_in[9];
  const float* bnb0 =(const float*)d_in[10];
  const float* ng0  =(const float*)d_in[11];
  const float* nb0  =(const float*)d_in[12];
  const float* wc1  =(const float*)d_in[13];
  const float* ws1  =(const float*)d_in[14];
  const float* bng1 =(const float*)d_in[15];
  const float* bnb1 =(const float*)d_in[16];
  const float* ng1  =(const float*)d_in[17];
  const float* nb1  =(const float*)d_in[18];
  const float* wc2  =(const float*)d_in[19];
  const float* ws2  =(const float*)d_in[20];
  const float* bng2 =(const float*)d_in[21];
  const float* bnb2 =(const float*)d_in[22];
  const float* ng2  =(const float*)d_in[23];
  const float* nb2  =(const float*)d_in[24];
  const float* fc1w =(const float*)d_in[25];
  const float* fc1b =(const float*)d_in[26];
  const float* fc2w =(const float*)d_in[27];
  const float* fc2b =(const float*)d_in[28];
  float* outp=(float*)d_out;

  char* base=(char*)d_ws;
  size_t off=0;
  auto alloc=[&](size_t nbytes)->void*{
    void* p=base+off; off=(off+nbytes+255)&~(size_t)255; return p; };

  float* psum0 =(float*)alloc((size_t)12*131072);      // 12 x [128][256] f32
  float* bc    =(float*)alloc(8192);                    // 8x256 sums
  float* ad    =(float*)alloc((size_t)12*2048);         // 12 x (a[256],d[256])
  float* wt_wc0=(float*)alloc((size_t)36*64*4);
  float* wt_ws0=(float*)alloc((size_t)3*256*64*4);
  float* wt_wc1=(float*)alloc((size_t)256*128*4);
  float* wt_ws1=(float*)alloc((size_t)3*512*128*4);
  float* wt_wc2=(float*)alloc((size_t)512*256*4);
  float* wt_ws2=(float*)alloc((size_t)3*1024*256*4);
  float* xT    =(float*)alloc((size_t)8*12000*9*4);
  float* B0    =(float*)alloc((size_t)49152000);
  float* B1    =(float*)alloc((size_t)49152000);
  float* B2    =(float*)alloc((size_t)49152000);
  if (off>ws_size) return;

  auto PS=[&](int i){ return psum0+(size_t)i*32768; };
  auto AA=[&](int i){ return ad+(size_t)i*512; };
  auto DD=[&](int i){ return ad+(size_t)i*512+256; };

  hipMemsetAsync(psum0,0,(size_t)12*131072+8192,stream);

  { int n=8*9*12000; transpose_in_kernel<<<(n+255)/256,256,0,stream>>>(x,xT,12000); }
  auto tw=[&](const float* w,float* wt,int K,int C){
    int n=K*C; transpose_w_kernel<<<(n+255)/256,256,0,stream>>>(w,wt,K,C); };
  tw(wc0,wt_wc0,36,64);
  for (int s=0;s<3;s++) tw(ws0+(size_t)s*16384, wt_ws0+(size_t)s*16384, 256,64);
  tw(wc1,wt_wc1,256,128);
  for (int s=0;s<3;s++) tw(ws1+(size_t)s*65536, wt_ws1+(size_t)s*65536, 512,128);
  tw(wc2,wt_wc2,512,256);
  for (int s=0;s<3;s++) tw(ws2+(size_t)s*262144, wt_ws2+(size_t)s*262144, 1024,256);

  auto fin=[&](int i,const float* g,const float* bb,int C,float invN){
    finalize_kernel<<<1,256,0,stream>>>(PS(i),g,bb,AA(i),DD(i),C,invN); };

  // -------- stage 0: F=12000, 9 -> 64 --------
  {
    const int F=12000; const float invN=1.f/(8.f*F);
    launch_conv<9,64,false,true>(xT,nbr0,wt_wc0,nullptr,nullptr,B0,PS(0),F,stream);
    fin(0,bng0,bnb0,64,invN);
    launch_conv<64,64,true,true>(B0,nbr0,wt_ws0,AA(0),DD(0),B1,PS(1),F,stream);
    fin(1,bng0+64,bnb0+64,64,invN);
    launch_conv<64,64,true,true>(B1,nbr0,wt_ws0+16384,AA(1),DD(1),B2,PS(2),F,stream);
    fin(2,bng0+128,bnb0+128,64,invN);
    launch_conv<64,64,true,false>(B2,nbr0,wt_ws0+32768,AA(2),DD(2),B1,nullptr,F,stream);
    int n4=8*F*64/4;
    int g=(n4+255)/256; if (g>2048) g=2048;
    add_relu_stats_kernel<64><<<g,256,0,stream>>>(B0,B1,PS(3),n4);
    fin(3,ng0,nb0,64,invN);
    int n4p=8*9000*16; int gp=(n4p+255)/256; if (gp>2048) gp=2048;
    pool_kernel<<<gp,256,0,stream>>>(B1,pool0,AA(3),DD(3),B2,16,F,9000,n4p);
  }
  // -------- stage 1: F=9000, 64 -> 128 --------
  {
    const int F=9000; const float invN=1.f/(8.f*F);
    launch_conv<64,128,false,true>(B2,nbr1,wt_wc1,nullptr,nullptr,B0,PS(4),F,stream);
    fin(4,bng1,bnb1,128,invN);
    launch_conv<128,128,true,true>(B0,nbr1,wt_ws1,AA(4),DD(4),B1,PS(5),F,stream);
    fin(5,bng1+128,bnb1+128,128,invN);
    launch_conv<128,128,true,true>(B1,nbr1,wt_ws1+65536,AA(5),DD(5),B2,PS(6),F,stream);
    fin(6,bng1+256,bnb1+256,128,invN);
    launch_conv<128,128,true,false>(B2,nbr1,wt_ws1+131072,AA(6),DD(6),B1,nullptr,F,stream);
    int n4=8*F*128/4;
    int g=(n4+255)/256; if (g>2048) g=2048;
    add_relu_stats_kernel<128><<<g,256,0,stream>>>(B0,B1,PS(7),n4);
    fin(7,ng1,nb1,128,invN);
    int n4p=8*6000*32; int gp=(n4p+255)/256; if (gp>2048) gp=2048;
    pool_kernel<<<gp,256,0,stream>>>(B1,pool1,AA(7),DD(7),B0,32,F,6000,n4p);
  }
  // -------- stage 2: F=6000, 128 -> 256 --------
  {
    const int F=6000; const float invN=1.f/(8.f*F);
    launch_conv<128,256,false,true>(B0,nbr2,wt_wc2,nullptr,nullptr,B1,PS(8),F,stream);
    fin(8,bng2,bnb2,256,invN);
    launch_conv<256,256,true,true>(B1,nbr2,wt_ws2,AA(8),DD(8),B2,PS(9),F,stream);
    fin(9,bng2+256,bnb2+256,256,invN);
    launch_conv<256,256,true,true>(B2,nbr2,wt_ws2+262144,AA(9),DD(9),B0,PS(10),F,stream);
    fin(10,bng2+512,bnb2+512,256,invN);
    launch_conv<256,256,true,false>(B0,nbr2,wt_ws2+524288,AA(10),DD(10),B2,nullptr,F,stream);
    int n4=8*F*256/4;
    int g=(n4+255)/256; if (g>2048) g=2048;
    add_relu_stats_kernel<256><<<g,256,0,stream>>>(B1,B2,PS(11),n4);
    fin(11,ng2,nb2,256,invN);
    int n4p=8*4000*64; int gp=(n4p+255)/256; if (gp>2048) gp=2048;
    pool_kernel<<<gp,256,0,stream>>>(B2,pool2,AA(11),DD(11),B0,64,F,4000,n4p);
    colsum_kernel<<<dim3(16,8),256,0,stream>>>(B0,bc,4000,250);
  }
  head_kernel<<<1,256,0,stream>>>(bc,fc1w,fc1b,fc2w,fc2b,outp,1.f/4000.f);
}

// Round 2
// 1222.940 us; speedup vs baseline: 2.9342x; 2.9342x over previous
//
#include <hip/hip_runtime.h>
#include <math.h>

#define NPART 64
#define TILE_F 16

typedef unsigned short u16;
typedef __attribute__((ext_vector_type(8))) short short8;
typedef __attribute__((ext_vector_type(4))) float f32x4;

__device__ __forceinline__ float relu_(float v){ return fmaxf(v, 0.f); }

__device__ __forceinline__ u16 f2bf(float x){
  unsigned u = __float_as_uint(x);
  u = (u + 0x7fffu + ((u >> 16) & 1u)) >> 16;
  return (u16)u;
}

static __device__ __forceinline__ f32x4 mfma_bf16(short8 a, short8 b, f32x4 c){
  asm("v_mfma_f32_16x16x32_bf16 %0, %1, %2, %0" : "+v"(c) : "v"(a), "v"(b));
  return c;
}

// ---------------------------------------------------------------------------
// MFMA mesh-conv: out[r,o] = sum_k G[r,k] * W[o,k],  r = b*F + f, k = 4c + j
// G built on the fly (gather + 4 features) into double-buffered swizzled LDS.
// W pre-converted to bf16 in original [cout][cin*4] layout (= B^T, k-contig).
// ---------------------------------------------------------------------------
template<int CIN,int COUT,bool BN,bool STATS>
__global__ __launch_bounds__(2*COUT) void mconv_kernel(
    const float* __restrict__ xin, const int* __restrict__ nbr,
    const u16* __restrict__ wbf, const float* __restrict__ bn_a,
    const float* __restrict__ bn_d, float* __restrict__ out,
    float* __restrict__ psum, int F)
{
  constexpr int T     = 2*COUT;
  constexpr int K     = 4*CIN;
  constexpr int KSTEP = T/4;          // k per LDS tile step
  constexpr int NSTEP = K/KSTEP;
  constexpr int CC    = KSTEP/16;     // channel-quads per row per step
  constexpr int CSTEP = KSTEP/4;      // channels per step
  constexpr int SLOTS = KSTEP/8;      // 16B slots per row
  constexpr int SMASK = (SLOTS < 8 ? SLOTS : 8) - 1;

  __shared__ __align__(16) u16 Gs[2][64*SLOTS*8];
  __shared__ float ls[STATS?COUT:1];
  __shared__ float lq[STATS?COUT:1];

  const int t    = threadIdx.x;
  const int lane = t & 63;
  const int wid  = t >> 6;
  const int wm   = wid & 1;
  const int wn   = wid >> 1;
  const int l15  = lane & 15;
  const int kq   = lane >> 4;

  if (STATS){ for (int i=t;i<COUT;i+=T){ ls[i]=0.f; lq[i]=0.f; } }

  // ---- G-build setup: fixed row per thread ----
  const int gr = t / CC;              // row in tile 0..63
  const int c4 = t % CC;              // channel-quad within step
  const float *p0,*p1,*p2,*p3;
  {
    int rg = blockIdx.x*64 + gr;
    int b  = rg / F;
    int f  = rg - b*F;
    int i1 = nbr[f*3+0], i2 = nbr[f*3+1], i3 = nbr[f*3+2];
    const float* xb = xin + (size_t)b*F*CIN + c4*4;
    p0 = xb + (size_t)f *CIN;
    p1 = xb + (size_t)i1*CIN;
    p2 = xb + (size_t)i2*CIN;
    p3 = xb + (size_t)i3*CIN;
  }

  f32x4 acc[2][4];
  #pragma unroll
  for (int i=0;i<2;i++)
    #pragma unroll
    for (int j=0;j<4;j++){ f32x4 z={0.f,0.f,0.f,0.f}; acc[i][j]=z; }

  auto ld=[&](int s, float4&S,float4&N1,float4&N2,float4&N3,float4&A4,float4&D4){
    S  = *(const float4*)(p0 + (size_t)s*CSTEP);
    N1 = *(const float4*)(p1 + (size_t)s*CSTEP);
    N2 = *(const float4*)(p2 + (size_t)s*CSTEP);
    N3 = *(const float4*)(p3 + (size_t)s*CSTEP);
    if constexpr (BN){
      A4 = *(const float4*)(bn_a + s*CSTEP + c4*4);
      D4 = *(const float4*)(bn_d + s*CSTEP + c4*4);
    }
  };

  auto bw=[&](int buf, float4 S,float4 N1,float4 N2,float4 N3,float4 A4,float4 D4){
    if constexpr (BN){
      S.x =fmaf(relu_(S.x ),A4.x,D4.x); S.y =fmaf(relu_(S.y ),A4.y,D4.y);
      S.z =fmaf(relu_(S.z ),A4.z,D4.z); S.w =fmaf(relu_(S.w ),A4.w,D4.w);
      N1.x=fmaf(relu_(N1.x),A4.x,D4.x); N1.y=fmaf(relu_(N1.y),A4.y,D4.y);
      N1.z=fmaf(relu_(N1.z),A4.z,D4.z); N1.w=fmaf(relu_(N1.w),A4.w,D4.w);
      N2.x=fmaf(relu_(N2.x),A4.x,D4.x); N2.y=fmaf(relu_(N2.y),A4.y,D4.y);
      N2.z=fmaf(relu_(N2.z),A4.z,D4.z); N2.w=fmaf(relu_(N2.w),A4.w,D4.w);
      N3.x=fmaf(relu_(N3.x),A4.x,D4.x); N3.y=fmaf(relu_(N3.y),A4.y,D4.y);
      N3.z=fmaf(relu_(N3.z),A4.z,D4.z); N3.w=fmaf(relu_(N3.w),A4.w,D4.w);
    }
    short8 lo, hi;
    #define FEAT(dst,i0,sv,av,bv,cv) \
      dst[i0+0]=(short)f2bf(sv); \
      dst[i0+1]=(short)f2bf(av+bv+cv); \
      dst[i0+2]=(short)f2bf(fabsf(av-bv)+fabsf(bv-cv)+fabsf(cv-av)); \
      dst[i0+3]=(short)f2bf(fmaxf(fmaxf(av,bv),cv));
    FEAT(lo,0,S.x,N1.x,N2.x,N3.x)
    FEAT(lo,4,S.y,N1.y,N2.y,N3.y)
    FEAT(hi,0,S.z,N1.z,N2.z,N3.z)
    FEAT(hi,4,S.w,N1.w,N2.w,N3.w)
    #undef FEAT
    const int ro = gr*SLOTS;
    *(short8*)&Gs[buf][(size_t)(ro + ((2*c4  ) ^ (gr&SMASK)))*8] = lo;
    *(short8*)&Gs[buf][(size_t)(ro + ((2*c4+1) ^ (gr&SMASK)))*8] = hi;
  };

  auto mf=[&](int buf, int s){
    const u16* g = &Gs[buf][0];
    const int r0 = wm*32 + l15;
    const int r1 = r0 + 16;
    #pragma unroll
    for (int kk=0;kk<KSTEP;kk+=32){
      const int sl = (kk>>3) + kq;
      short8 a0 = *(const short8*)&g[(size_t)(r0*SLOTS + (sl ^ (r0&SMASK)))*8];
      short8 a1 = *(const short8*)&g[(size_t)(r1*SLOTS + (sl ^ (r1&SMASK)))*8];
      const size_t kgl = (size_t)s*KSTEP + kk + kq*8;
      #pragma unroll
      for (int cg=0;cg<4;cg++){
        const int col = wn*64 + cg*16 + l15;
        short8 bb = *(const short8*)&wbf[(size_t)col*K + kgl];
        acc[0][cg] = mfma_bf16(a0, bb, acc[0][cg]);
        acc[1][cg] = mfma_bf16(a1, bb, acc[1][cg]);
      }
    }
  };

  // ---- prologue: build step 0 ----
  {
    float4 S,N1,N2,N3,A4={0,0,0,0},D4={0,0,0,0};
    ld(0,S,N1,N2,N3,A4,D4);
    bw(0,S,N1,N2,N3,A4,D4);
  }
  __syncthreads();

  #pragma unroll
  for (int s=0;s<NSTEP;s++){
    float4 S={0,0,0,0},N1={0,0,0,0},N2={0,0,0,0},N3={0,0,0,0},A4={0,0,0,0},D4={0,0,0,0};
    if (s+1<NSTEP) ld(s+1,S,N1,N2,N3,A4,D4);   // issue gather early
    mf(s&1, s);
    if (s+1<NSTEP) bw((s+1)&1,S,N1,N2,N3,A4,D4);
    __syncthreads();
  }

  // ---- epilogue: store + relu stats ----
  #pragma unroll
  for (int cg=0;cg<4;cg++){
    const int col = wn*64 + cg*16 + l15;
    float rs=0.f, rq=0.f;
    #pragma unroll
    for (int rg=0;rg<2;rg++){
      const size_t rbase = (size_t)blockIdx.x*64 + wm*32 + rg*16 + kq*4;
      #pragma unroll
      for (int q=0;q<4;q++){
        float v = acc[rg][cg][q];
        out[(rbase+q)*COUT + col] = v;
        if (STATS){ float rv = fmaxf(v,0.f); rs += rv; rq += rv*rv; }
      }
    }
    if (STATS){ atomicAdd(&ls[col],rs); atomicAdd(&lq[col],rq); }
  }
  if (STATS){
    __syncthreads();
    const int part = blockIdx.x & (NPART-1);
    for (int i=t;i<COUT;i+=T){
      atomicAdd(&psum[(size_t)part*256+i], ls[i]);
      atomicAdd(&psum[(size_t)(NPART+part)*256+i], lq[i]);
    }
  }
}

// ---------------------------------------------------------------------------
// fp32 conv path (kept only for the tiny 9->64 conv, K=36)
// ---------------------------------------------------------------------------
template<int CIN,int COUT,bool BN,bool STATS>
__global__ __launch_bounds__(256) void conv_kernel(
    const float* __restrict__ xin, const int* __restrict__ nbr,
    const float* __restrict__ Wt, const float* __restrict__ bn_a,
    const float* __restrict__ bn_d,
    float* __restrict__ out, float* __restrict__ psum, int F)
{
  constexpr int K = 4*CIN;
  constexpr int ROWLEN = K + 4;
  __shared__ float Gs[TILE_F][ROWLEN];
  __shared__ int   nI[TILE_F*3];
  __shared__ float ls[STATS?COUT:1];
  __shared__ float lq[STATS?COUT:1];
  const int t = threadIdx.x;
  const int fbase = blockIdx.x*TILE_F;
  const int b = blockIdx.y;
  const float* __restrict__ xb = xin + (size_t)b*F*CIN;

  if (t < TILE_F*3){ int fi=t/3, j=t-fi*3; int fg=fbase+fi; nI[t]=(fg<F)?nbr[fg*3+j]:0; }
  if (STATS){ for (int i=t;i<COUT;i+=256){ ls[i]=0.f; lq[i]=0.f; } }
  __syncthreads();

  for (int idx=t; idx<TILE_F*CIN; idx+=256){
    int fi=idx/CIN, c=idx-fi*CIN;
    int fg=fbase+fi;
    float* dst=&Gs[fi][4*c];
    if (fg<F){
      int i1=nI[fi*3], i2=nI[fi*3+1], i3=nI[fi*3+2];
      float s =xb[(size_t)fg*CIN+c];
      float v1=xb[(size_t)i1*CIN+c];
      float v2=xb[(size_t)i2*CIN+c];
      float v3=xb[(size_t)i3*CIN+c];
      if (BN){ float a=bn_a[c], dd=bn_d[c];
        s=fmaf(relu_(s),a,dd); v1=fmaf(relu_(v1),a,dd);
        v2=fmaf(relu_(v2),a,dd); v3=fmaf(relu_(v3),a,dd); }
      dst[0]=s; dst[1]=v1+v2+v3;
      dst[2]=fabsf(v1-v2)+fabsf(v2-v3)+fabsf(v3-v1);
      dst[3]=fmaxf(fmaxf(v1,v2),v3);
    } else { dst[0]=0.f;dst[1]=0.f;dst[2]=0.f;dst[3]=0.f; }
  }
  __syncthreads();

  constexpr int OQ=COUT/4;
  constexpr int R=256/OQ;
  constexpr int FPT=TILE_F/R;
  const int col=t%OQ, row=t/OQ;
  const int o0=col*4, f0=row*FPT;
  float4 acc[FPT];
  #pragma unroll
  for (int fi=0;fi<FPT;fi++){ acc[fi].x=0.f;acc[fi].y=0.f;acc[fi].z=0.f;acc[fi].w=0.f; }

  for (int k=0;k<K;k+=4){
    float4 w0=*(const float4*)&Wt[(size_t)(k+0)*COUT+o0];
    float4 w1=*(const float4*)&Wt[(size_t)(k+1)*COUT+o0];
    float4 w2=*(const float4*)&Wt[(size_t)(k+2)*COUT+o0];
    float4 w3=*(const float4*)&Wt[(size_t)(k+3)*COUT+o0];
    #pragma unroll
    for (int fi=0;fi<FPT;fi++){
      float4 g=*(const float4*)&Gs[f0+fi][k];
      acc[fi].x=fmaf(g.x,w0.x,fmaf(g.y,w1.x,fmaf(g.z,w2.x,fmaf(g.w,w3.x,acc[fi].x))));
      acc[fi].y=fmaf(g.x,w0.y,fmaf(g.y,w1.y,fmaf(g.z,w2.y,fmaf(g.w,w3.y,acc[fi].y))));
      acc[fi].z=fmaf(g.x,w0.z,fmaf(g.y,w1.z,fmaf(g.z,w2.z,fmaf(g.w,w3.z,acc[fi].z))));
      acc[fi].w=fmaf(g.x,w0.w,fmaf(g.y,w1.w,fmaf(g.z,w2.w,fmaf(g.w,w3.w,acc[fi].w))));
    }
  }

  float4 rs={0,0,0,0}, rq={0,0,0,0};
  #pragma unroll
  for (int fi=0;fi<FPT;fi++){
    int fg=fbase+f0+fi;
    if (fg<F){
      *(float4*)&out[((size_t)b*F+fg)*COUT+o0]=acc[fi];
      if (STATS){
        float rx=relu_(acc[fi].x), ry=relu_(acc[fi].y);
        float rz=relu_(acc[fi].z), rw=relu_(acc[fi].w);
        rs.x+=rx; rs.y+=ry; rs.z+=rz; rs.w+=rw;
        rq.x+=rx*rx; rq.y+=ry*ry; rq.z+=rz*rz; rq.w+=rw*rw;
      }
    }
  }
  if (STATS){
    atomicAdd(&ls[o0+0],rs.x); atomicAdd(&ls[o0+1],rs.y);
    atomicAdd(&ls[o0+2],rs.z); atomicAdd(&ls[o0+3],rs.w);
    atomicAdd(&lq[o0+0],rq.x); atomicAdd(&lq[o0+1],rq.y);
    atomicAdd(&lq[o0+2],rq.z); atomicAdd(&lq[o0+3],rq.w);
    __syncthreads();
    int part=(blockIdx.y*gridDim.x+blockIdx.x)&(NPART-1);
    for (int i=t;i<COUT;i+=256){
      atomicAdd(&psum[(size_t)part*256+i], ls[i]);
      atomicAdd(&psum[(size_t)(NPART+part)*256+i], lq[i]);
    }
  }
}

__global__ __launch_bounds__(256) void finalize_kernel(
    const float* __restrict__ psum, const float* __restrict__ g,
    const float* __restrict__ bb, float* __restrict__ a, float* __restrict__ d,
    int C, float invN)
{
  int c=threadIdx.x;
  if (c<C){
    float s=0.f,q=0.f;
    for (int p=0;p<NPART;p++){ s+=psum[(size_t)p*256+c]; q+=psum[(size_t)(NPART+p)*256+c]; }
    float m=s*invN, v=q*invN-m*m;
    float ai=g[c]*rsqrtf(v+1e-5f);
    a[c]=ai; d[c]=bb[c]-m*ai;
  }
}

template<int C>
__global__ __launch_bounds__(256) void add_relu_stats_kernel(
    const float* __restrict__ y0, float* __restrict__ z,
    float* __restrict__ psum, int n4)
{
  __shared__ float ls[C], lq[C];
  for (int i=threadIdx.x;i<C;i+=256){ ls[i]=0.f; lq[i]=0.f; }
  __syncthreads();
  int i0=blockIdx.x*256+threadIdx.x;
  int stride=gridDim.x*256;
  int c0=(i0*4)%C;
  float4 rs={0,0,0,0}, rq={0,0,0,0};
  for (int i=i0;i<n4;i+=stride){
    float4 a=*(const float4*)&y0[(size_t)i*4];
    float4 bq=*(const float4*)&z[(size_t)i*4];
    float4 v;
    v.x=relu_(a.x+bq.x); v.y=relu_(a.y+bq.y);
    v.z=relu_(a.z+bq.z); v.w=relu_(a.w+bq.w);
    *(float4*)&z[(size_t)i*4]=v;
    rs.x+=v.x; rs.y+=v.y; rs.z+=v.z; rs.w+=v.w;
    rq.x+=v.x*v.x; rq.y+=v.y*v.y; rq.z+=v.z*v.z; rq.w+=v.w*v.w;
  }
  atomicAdd(&ls[c0+0],rs.x); atomicAdd(&ls[c0+1],rs.y);
  atomicAdd(&ls[c0+2],rs.z); atomicAdd(&ls[c0+3],rs.w);
  atomicAdd(&lq[c0+0],rq.x); atomicAdd(&lq[c0+1],rq.y);
  atomicAdd(&lq[c0+2],rq.z); atomicAdd(&lq[c0+3],rq.w);
  __syncthreads();
  int part=blockIdx.x&(NPART-1);
  for (int i=threadIdx.x;i<C;i+=256){
    atomicAdd(&psum[(size_t)part*256+i],ls[i]);
    atomicAdd(&psum[(size_t)(NPART+part)*256+i],lq[i]);
  }
}

__global__ __launch_bounds__(256) void pool_kernel(
    const float* __restrict__ z, const int* __restrict__ pl,
    const float* __restrict__ a, const float* __restrict__ d,
    float* __restrict__ out, int C4, int F, int Fn, int n4)
{
  const int C=C4*4;
  for (int i=blockIdx.x*256+threadIdx.x; i<n4; i+=gridDim.x*256){
    int c4=i%C4; int rest=i/C4; int p=rest%Fn; int b=rest/Fn;
    int p0=pl[p*3], p1=pl[p*3+1], p2=pl[p*3+2];
    float4 a4=*(const float4*)&a[4*c4], d4=*(const float4*)&d[4*c4];
    float4 v0=*(const float4*)&z[((size_t)b*F+p0)*C+4*c4];
    float4 v1=*(const float4*)&z[((size_t)b*F+p1)*C+4*c4];
    float4 v2=*(const float4*)&z[((size_t)b*F+p2)*C+4*c4];
    float4 r;
    r.x=(relu_(fmaf(v0.x,a4.x,d4.x))+relu_(fmaf(v1.x,a4.x,d4.x))+relu_(fmaf(v2.x,a4.x,d4.x)))*(1.f/3.f);
    r.y=(relu_(fmaf(v0.y,a4.y,d4.y))+relu_(fmaf(v1.y,a4.y,d4.y))+relu_(fmaf(v2.y,a4.y,d4.y)))*(1.f/3.f);
    r.z=(relu_(fmaf(v0.z,a4.z,d4.z))+relu_(fmaf(v1.z,a4.z,d4.z))+relu_(fmaf(v2.z,a4.z,d4.z)))*(1.f/3.f);
    r.w=(relu_(fmaf(v0.w,a4.w,d4.w))+relu_(fmaf(v1.w,a4.w,d4.w))+relu_(fmaf(v2.w,a4.w,d4.w)))*(1.f/3.f);
    *(float4*)&out[((size_t)b*Fn+p)*C+4*c4]=r;
  }
}

__global__ __launch_bounds__(256) void colsum_kernel(
    const float* __restrict__ x, float* __restrict__ bc, int F, int chunk)
{
  int b=blockIdx.y; int f0=blockIdx.x*chunk;
  int c=threadIdx.x;
  int fe=f0+chunk; if (fe>F) fe=F;
  float s=0.f;
  for (int f=f0;f<fe;f++) s+=x[((size_t)b*F+f)*256+c];
  atomicAdd(&bc[b*256+c], s);
}

__global__ __launch_bounds__(256) void head_kernel(
    const float* __restrict__ bc, const float* __restrict__ w1,
    const float* __restrict__ b1, const float* __restrict__ w2,
    const float* __restrict__ b2, float* __restrict__ outp, float invF)
{
  __shared__ float xm[8*256];
  __shared__ float h[8*128];
  int t=threadIdx.x;
  for (int i=t;i<2048;i+=256) xm[i]=bc[i]*invF;
  __syncthreads();
  #pragma unroll
  for (int r=0;r<4;r++){
    int idx=t+r*256; int b=idx>>7, j=idx&127;
    float s=b1[j];
    for (int c=0;c<256;c++) s=fmaf(xm[b*256+c],w1[j*256+c],s);
    h[idx]=relu_(s);
  }
  __syncthreads();
  if (t<8){
    float s=b2[0];
    for (int j=0;j<128;j++) s=fmaf(h[t*128+j],w2[j],s);
    outp[t]=1.f/(1.f+expf(-s));
  }
}

__global__ __launch_bounds__(256) void transpose_in_kernel(
    const float* __restrict__ x, float* __restrict__ xt, int F)
{
  int i=blockIdx.x*256+threadIdx.x;
  int total=8*9*F;
  if (i<total){ int f=i%F; int c=(i/F)%9; int b=i/(9*F);
    xt[((size_t)b*F+f)*9+c]=x[i]; }
}

__global__ __launch_bounds__(256) void transpose_w_kernel(
    const float* __restrict__ w, float* __restrict__ wt, int K, int COUT)
{
  int i=blockIdx.x*256+threadIdx.x;
  if (i<K*COUT){ int o=i/K, k=i-o*K; wt[(size_t)k*COUT+o]=w[i]; }
}

__global__ __launch_bounds__(256) void cvt_bf16_kernel(
    const float* __restrict__ w, u16* __restrict__ o, int n)
{
  int i=blockIdx.x*256+threadIdx.x;
  if (i<n) o[i]=f2bf(w[i]);
}

// ---------------------------------------------------------------------------

template<int CIN,int COUT,bool BN,bool STATS>
static void launch_mconv(const float* xin, const int* nbr, const u16* wbf,
                         const float* a, const float* d, float* out,
                         float* psum, int F, hipStream_t stream)
{
  int M = 8*F;
  mconv_kernel<CIN,COUT,BN,STATS><<<M/64, 2*COUT, 0, stream>>>(xin,nbr,wbf,a,d,out,psum,F);
}

extern "C" void kernel_launch(void* const* d_in, const int* in_sizes, int n_in,
                              void* d_out, int out_size, void* d_ws, size_t ws_size,
                              hipStream_t stream)
{
  const float* x    =(const float*)d_in[0];
  const int*  nbr0  =(const int*)d_in[1];
  const int*  pool0 =(const int*)d_in[2];
  const int*  nbr1  =(const int*)d_in[3];
  const int*  pool1 =(const int*)d_in[4];
  const int*  nbr2  =(const int*)d_in[5];
  const int*  pool2 =(const int*)d_in[6];
  const float* wc0  =(const float*)d_in[7];
  const float* ws0  =(const float*)d_in[8];
  const float* bng0 =(const float*)d_in[9];
  const float* bnb0 =(const float*)d_in[10];
  const float* ng0  =(const float*)d_in[11];
  const float* nb0  =(const float*)d_in[12];
  const float* wc1  =(const float*)d_in[13];
  const float* ws1  =(const float*)d_in[14];
  const float* bng1 =(const float*)d_in[15];
  const float* bnb1 =(const float*)d_in[16];
  const float* ng1  =(const float*)d_in[17];
  const float* nb1  =(const float*)d_in[18];
  const float* wc2  =(const float*)d_in[19];
  const float* ws2  =(const float*)d_in[20];
  const float* bng2 =(const float*)d_in[21];
  const float* bnb2 =(const float*)d_in[22];
  const float* ng2  =(const float*)d_in[23];
  const float* nb2  =(const float*)d_in[24];
  const float* fc1w =(const float*)d_in[25];
  const float* fc1b =(const float*)d_in[26];
  const float* fc2w =(const float*)d_in[27];
  const float* fc2b =(const float*)d_in[28];
  float* outp=(float*)d_out;

  char* base=(char*)d_ws;
  size_t off=0;
  auto alloc=[&](size_t nbytes)->void*{
    void* p=base+off; off=(off+nbytes+255)&~(size_t)255; return p; };

  float* psum0 =(float*)alloc((size_t)12*131072);
  float* bc    =(float*)alloc(8192);
  float* ad    =(float*)alloc((size_t)12*2048);
  float* wt_wc0=(float*)alloc((size_t)36*64*4);
  u16*   bws0  =(u16*)alloc((size_t)3*16384*2);
  u16*   bwc1  =(u16*)alloc((size_t)32768*2);
  u16*   bws1  =(u16*)alloc((size_t)3*65536*2);
  u16*   bwc2  =(u16*)alloc((size_t)131072*2);
  u16*   bws2  =(u16*)alloc((size_t)3*262144*2);
  float* xT    =(float*)alloc((size_t)8*12000*9*4);
  float* B0    =(float*)alloc((size_t)49152000);
  float* B1    =(float*)alloc((size_t)49152000);
  float* B2    =(float*)alloc((size_t)49152000);
  if (off>ws_size) return;

  auto PS=[&](int i){ return psum0+(size_t)i*32768; };
  auto AA=[&](int i){ return ad+(size_t)i*512; };
  auto DD=[&](int i){ return ad+(size_t)i*512+256; };

  hipMemsetAsync(psum0,0,(size_t)12*131072+8192,stream);

  { int n=8*9*12000; transpose_in_kernel<<<(n+255)/256,256,0,stream>>>(x,xT,12000); }
  { int n=36*64; transpose_w_kernel<<<(n+255)/256,256,0,stream>>>(wc0,wt_wc0,36,64); }
  auto cv=[&](const float* w,u16* o,int n){
    cvt_bf16_kernel<<<(n+255)/256,256,0,stream>>>(w,o,n); };
  cv(ws0,bws0,3*16384);
  cv(wc1,bwc1,32768);
  cv(ws1,bws1,3*65536);
  cv(wc2,bwc2,131072);
  cv(ws2,bws2,3*262144);

  auto fin=[&](int i,const float* g,const float* bb,int C,float invN){
    finalize_kernel<<<1,256,0,stream>>>(PS(i),g,bb,AA(i),DD(i),C,invN); };

  // -------- stage 0: F=12000, 9 -> 64 --------
  {
    const int F=12000; const float invN=1.f/(8.f*F);
    dim3 grid((F+TILE_F-1)/TILE_F, 8);
    conv_kernel<9,64,false,true><<<grid,256,0,stream>>>(xT,nbr0,wt_wc0,nullptr,nullptr,B0,PS(0),F);
    fin(0,bng0,bnb0,64,invN);
    launch_mconv<64,64,true,true>(B0,nbr0,bws0,AA(0),DD(0),B1,PS(1),F,stream);
    fin(1,bng0+64,bnb0+64,64,invN);
    launch_mconv<64,64,true,true>(B1,nbr0,bws0+16384,AA(1),DD(1),B2,PS(2),F,stream);
    fin(2,bng0+128,bnb0+128,64,invN);
    launch_mconv<64,64,true,false>(B2,nbr0,bws0+32768,AA(2),DD(2),B1,nullptr,F,stream);
    int n4=8*F*64/4;
    int g=(n4+255)/256; if (g>2048) g=2048;
    add_relu_stats_kernel<64><<<g,256,0,stream>>>(B0,B1,PS(3),n4);
    fin(3,ng0,nb0,64,invN);
    int n4p=8*9000*16; int gp=(n4p+255)/256; if (gp>2048) gp=2048;
    pool_kernel<<<gp,256,0,stream>>>(B1,pool0,AA(3),DD(3),B2,16,F,9000,n4p);
  }
  // -------- stage 1: F=9000, 64 -> 128 --------
  {
    const int F=9000; const float invN=1.f/(8.f*F);
    launch_mconv<64,128,false,true>(B2,nbr1,bwc1,nullptr,nullptr,B0,PS(4),F,stream);
    fin(4,bng1,bnb1,128,invN);
    launch_mconv<128,128,true,true>(B0,nbr1,bws1,AA(4),DD(4),B1,PS(5),F,stream);
    fin(5,bng1+128,bnb1+128,128,invN);
    launch_mconv<128,128,true,true>(B1,nbr1,bws1+65536,AA(5),DD(5),B2,PS(6),F,stream);
    fin(6,bng1+256,bnb1+256,128,invN);
    launch_mconv<128,128,true,false>(B2,nbr1,bws1+131072,AA(6),DD(6),B1,nullptr,F,stream);
    int n4=8*F*128/4;
    int g=(n4+255)/256; if (g>2048) g=2048;
    add_relu_stats_kernel<128><<<g,256,0,stream>>>(B0,B1,PS(7),n4);
    fin(7,ng1,nb1,128,invN);
    int n4p=8*6000*32; int gp=(n4p+255)/256; if (gp>2048) gp=2048;
    pool_kernel<<<gp,256,0,stream>>>(B1,pool1,AA(7),DD(7),B0,32,F,6000,n4p);
  }
  // -------- stage 2: F=6000, 128 -> 256 --------
  {
    const int F=6000; const float invN=1.f/(8.f*F);
    launch_mconv<128,256,false,true>(B0,nbr2,bwc2,nullptr,nullptr,B1,PS(8),F,stream);
    fin(8,bng2,bnb2,256,invN);
    launch_mconv<256,256,true,true>(B1,nbr2,bws2,AA(8),DD(8),B2,PS(9),F,stream);
    fin(9,bng2+256,bnb2+256,256,invN);
    launch_mconv<256,256,true,true>(B2,nbr2,bws2+262144,AA(9),DD(9),B0,PS(10),F,stream);
    fin(10,bng2+512,bnb2+512,256,invN);
    launch_mconv<256,256,true,false>(B0,nbr2,bws2+524288,AA(10),DD(10),B2,nullptr,F,stream);
    int n4=8*F*256/4;
    int g=(n4+255)/256; if (g>2048) g=2048;
    add_relu_stats_kernel<256><<<g,256,0,stream>>>(B1,B2,PS(11),n4);
    fin(11,ng2,nb2,256,invN);
    int n4p=8*4000*64; int gp=(n4p+255)/256; if (gp>2048) gp=2048;
    pool_kernel<<<gp,256,0,stream>>>(B2,pool2,AA(11),DD(11),B0,64,F,4000,n4p);
    colsum_kernel<<<dim3(16,8),256,0,stream>>>(B0,bc,4000,250);
  }
  head_kernel<<<1,256,0,stream>>>(bc,fc1w,fc1b,fc2w,fc2b,outp,1.f/4000.f);
}

// Round 3
// 1091.413 us; speedup vs baseline: 3.2878x; 1.1205x over previous
//
#include <hip/hip_runtime.h>
#include <math.h>

#define NPART 64
#define TILE_F 16

typedef unsigned short u16;
typedef __attribute__((ext_vector_type(8))) short short8;
typedef __attribute__((ext_vector_type(4))) float f32x4;

__device__ __forceinline__ float relu_(float v){ return fmaxf(v, 0.f); }

__device__ __forceinline__ u16 f2bf(float x){
  unsigned u = __float_as_uint(x);
  u = (u + 0x7fffu + ((u >> 16) & 1u)) >> 16;
  return (u16)u;
}

static __device__ __forceinline__ f32x4 mfma_bf16(short8 a, short8 b, f32x4 c){
  asm("v_mfma_f32_16x16x32_bf16 %0, %1, %2, %0" : "+v"(c) : "v"(a), "v"(b));
  return c;
}

// ---------------------------------------------------------------------------
// MFMA mesh-conv, 64x64 wave tile, KSTEP=64, B prefetch one slice ahead,
// BN finalize folded into prologue (reduces psum partials -> a,d in LDS).
//   out[r,o] = sum_k G[r,k] * W[o,k];  r = b*F+f, k = 4c+j
// ---------------------------------------------------------------------------
template<int CIN,int COUT,int WR,int NWR,bool BN,bool STATS>
__global__ __launch_bounds__(NWR*(COUT/64)*64) void mconv_kernel(
    const float* __restrict__ xin, const int* __restrict__ nbr,
    const u16* __restrict__ wbf,
    const float* __restrict__ ps_in, const float* __restrict__ gamma,
    const float* __restrict__ beta,
    float* __restrict__ out, float* __restrict__ psum,
    int F, float invN)
{
  constexpr int nWc = COUT/64;
  constexpr int T   = NWR*nWc*64;
  constexpr int BR  = NWR*WR;
  constexpr int K   = 4*CIN;
  constexpr int NSTEP = CIN/16;       // 16 channels (64 k) per step
  constexpr int ITEMS = (BR*4)/T;     // gather work items per thread
  constexpr int NRF   = WR/16;        // row fragments per wave

  __shared__ __align__(16) u16 Gs[2][BR*64];
  __shared__ float ls[STATS?COUT:1], lq[STATS?COUT:1];
  __shared__ float aS[BN?CIN:1], dS[BN?CIN:1];

  const int t=threadIdx.x, lane=t&63, wid=t>>6;
  const int wm=wid/nWc, wc=wid%nWc;
  const int l15=lane&15, kq=lane>>4;

  if (BN){
    for (int c=t;c<CIN;c+=T){
      float s=0.f,q=0.f;
      #pragma unroll 4
      for (int p=0;p<NPART;p++){ s+=ps_in[p*256+c]; q+=ps_in[(NPART+p)*256+c]; }
      float m=s*invN, v=q*invN-m*m;
      float ai=gamma[c]*rsqrtf(v+1e-5f);
      aS[c]=ai; dS[c]=beta[c]-m*ai;
    }
  }
  if (STATS){ for (int i=t;i<COUT;i+=T){ ls[i]=0.f; lq[i]=0.f; } }
  __syncthreads();

  // ---- gather pointers (fixed rows/channel-quads per thread) ----
  const float *P0[ITEMS],*P1[ITEMS],*P2[ITEMS],*P3[ITEMS];
  #pragma unroll
  for (int i=0;i<ITEMS;i++){
    int idx=i*T+t, gr=idx>>2, c4q=idx&3;
    int rg=blockIdx.x*BR+gr;
    int b=rg/F, f=rg-b*F;
    int i1=nbr[f*3+0], i2=nbr[f*3+1], i3=nbr[f*3+2];
    const float* xb=xin+(size_t)b*F*CIN+c4q*4;
    P0[i]=xb+(size_t)f *CIN; P1[i]=xb+(size_t)i1*CIN;
    P2[i]=xb+(size_t)i2*CIN; P3[i]=xb+(size_t)i3*CIN;
  }

  const u16* wp = wbf + (size_t)(wc*64+l15)*K + kq*8;
  auto BLD=[&](int cg,int j)->short8{
    return *(const short8*)(wp + (size_t)cg*16*K + (size_t)j*32);
  };
  auto ADS=[&](int pb,int rr,int h)->short8{
    int r=wm*WR+rr*16+l15;
    int sl=h*4+kq;
    return *(const short8*)&Gs[pb][(size_t)r*64 + (size_t)((sl^(r&7))*8)];
  };
  auto GLD=[&](int s,float4 (&g)[ITEMS][4]){
    #pragma unroll
    for (int i=0;i<ITEMS;i++){
      g[i][0]=*(const float4*)(P0[i]+s*16);
      g[i][1]=*(const float4*)(P1[i]+s*16);
      g[i][2]=*(const float4*)(P2[i]+s*16);
      g[i][3]=*(const float4*)(P3[i]+s*16);
    }
  };
  auto BLDW=[&](int pb,int s,float4 (&g)[ITEMS][4]){
    #pragma unroll
    for (int i=0;i<ITEMS;i++){
      int idx=i*T+t, gr=idx>>2, c4q=idx&3;
      float4 S=g[i][0],N1=g[i][1],N2=g[i][2],N3=g[i][3];
      if (BN){
        float4 a4=*(const float4*)&aS[s*16+c4q*4];
        float4 d4=*(const float4*)&dS[s*16+c4q*4];
        S.x =fmaf(relu_(S.x ),a4.x,d4.x); S.y =fmaf(relu_(S.y ),a4.y,d4.y);
        S.z =fmaf(relu_(S.z ),a4.z,d4.z); S.w =fmaf(relu_(S.w ),a4.w,d4.w);
        N1.x=fmaf(relu_(N1.x),a4.x,d4.x); N1.y=fmaf(relu_(N1.y),a4.y,d4.y);
        N1.z=fmaf(relu_(N1.z),a4.z,d4.z); N1.w=fmaf(relu_(N1.w),a4.w,d4.w);
        N2.x=fmaf(relu_(N2.x),a4.x,d4.x); N2.y=fmaf(relu_(N2.y),a4.y,d4.y);
        N2.z=fmaf(relu_(N2.z),a4.z,d4.z); N2.w=fmaf(relu_(N2.w),a4.w,d4.w);
        N3.x=fmaf(relu_(N3.x),a4.x,d4.x); N3.y=fmaf(relu_(N3.y),a4.y,d4.y);
        N3.z=fmaf(relu_(N3.z),a4.z,d4.z); N3.w=fmaf(relu_(N3.w),a4.w,d4.w);
      }
      short8 lo,hi;
      #define FEAT(dst,i0,sv,av,bv,cv) \
        dst[i0+0]=(short)f2bf(sv); \
        dst[i0+1]=(short)f2bf(av+bv+cv); \
        dst[i0+2]=(short)f2bf(fabsf(av-bv)+fabsf(bv-cv)+fabsf(cv-av)); \
        dst[i0+3]=(short)f2bf(fmaxf(fmaxf(av,bv),cv));
      FEAT(lo,0,S.x,N1.x,N2.x,N3.x)
      FEAT(lo,4,S.y,N1.y,N2.y,N3.y)
      FEAT(hi,0,S.z,N1.z,N2.z,N3.z)
      FEAT(hi,4,S.w,N1.w,N2.w,N3.w)
      #undef FEAT
      u16* rowp=&Gs[pb][(size_t)gr*64];
      *(short8*)&rowp[(size_t)(((2*c4q  )^(gr&7))*8)]=lo;
      *(short8*)&rowp[(size_t)(((2*c4q+1)^(gr&7))*8)]=hi;
    }
  };

  f32x4 acc[NRF][4];
  #pragma unroll
  for (int rr=0;rr<NRF;rr++)
    #pragma unroll
    for (int cg=0;cg<4;cg++){ f32x4 z={0.f,0.f,0.f,0.f}; acc[rr][cg]=z; }

  short8 B0[4],B1[4];
  #pragma unroll
  for (int cg=0;cg<4;cg++) B0[cg]=BLD(cg,0);
  #pragma unroll
  for (int cg=0;cg<4;cg++) B1[cg]=BLD(cg,1);

  { float4 g0[ITEMS][4]; GLD(0,g0); BLDW(0,0,g0); }
  __syncthreads();

  #pragma unroll 2
  for (int s=0;s<NSTEP;s++){
    const int pb=s&1;
    float4 g[ITEMS][4];
    if (s+1<NSTEP) GLD(s+1,g);               // issue gathers for next step
    short8 A[NRF];
    #pragma unroll
    for (int rr=0;rr<NRF;rr++) A[rr]=ADS(pb,rr,0);
    #pragma unroll
    for (int rr=0;rr<NRF;rr++)
      #pragma unroll
      for (int cg=0;cg<4;cg++) acc[rr][cg]=mfma_bf16(A[rr],B0[cg],acc[rr][cg]);
    if (s+1<NSTEP){
      #pragma unroll
      for (int cg=0;cg<4;cg++) B0[cg]=BLD(cg,2*(s+1));   // prefetch next slice
    }
    #pragma unroll
    for (int rr=0;rr<NRF;rr++) A[rr]=ADS(pb,rr,1);
    #pragma unroll
    for (int rr=0;rr<NRF;rr++)
      #pragma unroll
      for (int cg=0;cg<4;cg++) acc[rr][cg]=mfma_bf16(A[rr],B1[cg],acc[rr][cg]);
    if (s+1<NSTEP){
      #pragma unroll
      for (int cg=0;cg<4;cg++) B1[cg]=BLD(cg,2*(s+1)+1);
      BLDW(pb^1,s+1,g);                      // features -> other buffer
    }
    __syncthreads();
  }

  // ---- epilogue: store + relu stats ----
  #pragma unroll
  for (int cg=0;cg<4;cg++){
    const int col=wc*64+cg*16+l15;
    float rs=0.f,rq=0.f;
    #pragma unroll
    for (int rr=0;rr<NRF;rr++){
      const size_t rbase=(size_t)blockIdx.x*BR + wm*WR + rr*16 + kq*4;
      #pragma unroll
      for (int q=0;q<4;q++){
        float v=acc[rr][cg][q];
        out[(rbase+q)*COUT+col]=v;
        if (STATS){ float rv=relu_(v); rs+=rv; rq+=rv*rv; }
      }
    }
    if (STATS){ atomicAdd(&ls[col],rs); atomicAdd(&lq[col],rq); }
  }
  if (STATS){
    __syncthreads();
    const int part=blockIdx.x&(NPART-1);
    for (int i=t;i<COUT;i+=T){
      atomicAdd(&psum[(size_t)part*256+i],ls[i]);
      atomicAdd(&psum[(size_t)(NPART+part)*256+i],lq[i]);
    }
  }
}

// ---------------------------------------------------------------------------
// fp32 conv path (tiny 9->64 conv only)
// ---------------------------------------------------------------------------
template<int CIN,int COUT,bool BN,bool STATS>
__global__ __launch_bounds__(256) void conv_kernel(
    const float* __restrict__ xin, const int* __restrict__ nbr,
    const float* __restrict__ Wt, const float* __restrict__ bn_a,
    const float* __restrict__ bn_d,
    float* __restrict__ out, float* __restrict__ psum, int F)
{
  constexpr int K = 4*CIN;
  constexpr int ROWLEN = K + 4;
  __shared__ float Gs[TILE_F][ROWLEN];
  __shared__ int   nI[TILE_F*3];
  __shared__ float ls[STATS?COUT:1];
  __shared__ float lq[STATS?COUT:1];
  const int t = threadIdx.x;
  const int fbase = blockIdx.x*TILE_F;
  const int b = blockIdx.y;
  const float* __restrict__ xb = xin + (size_t)b*F*CIN;

  if (t < TILE_F*3){ int fi=t/3, j=t-fi*3; int fg=fbase+fi; nI[t]=(fg<F)?nbr[fg*3+j]:0; }
  if (STATS){ for (int i=t;i<COUT;i+=256){ ls[i]=0.f; lq[i]=0.f; } }
  __syncthreads();

  for (int idx=t; idx<TILE_F*CIN; idx+=256){
    int fi=idx/CIN, c=idx-fi*CIN;
    int fg=fbase+fi;
    float* dst=&Gs[fi][4*c];
    if (fg<F){
      int i1=nI[fi*3], i2=nI[fi*3+1], i3=nI[fi*3+2];
      float s =xb[(size_t)fg*CIN+c];
      float v1=xb[(size_t)i1*CIN+c];
      float v2=xb[(size_t)i2*CIN+c];
      float v3=xb[(size_t)i3*CIN+c];
      if (BN){ float a=bn_a[c], dd=bn_d[c];
        s=fmaf(relu_(s),a,dd); v1=fmaf(relu_(v1),a,dd);
        v2=fmaf(relu_(v2),a,dd); v3=fmaf(relu_(v3),a,dd); }
      dst[0]=s; dst[1]=v1+v2+v3;
      dst[2]=fabsf(v1-v2)+fabsf(v2-v3)+fabsf(v3-v1);
      dst[3]=fmaxf(fmaxf(v1,v2),v3);
    } else { dst[0]=0.f;dst[1]=0.f;dst[2]=0.f;dst[3]=0.f; }
  }
  __syncthreads();

  constexpr int OQ=COUT/4;
  constexpr int R=256/OQ;
  constexpr int FPT=TILE_F/R;
  const int col=t%OQ, row=t/OQ;
  const int o0=col*4, f0=row*FPT;
  float4 acc[FPT];
  #pragma unroll
  for (int fi=0;fi<FPT;fi++){ acc[fi].x=0.f;acc[fi].y=0.f;acc[fi].z=0.f;acc[fi].w=0.f; }

  for (int k=0;k<K;k+=4){
    float4 w0=*(const float4*)&Wt[(size_t)(k+0)*COUT+o0];
    float4 w1=*(const float4*)&Wt[(size_t)(k+1)*COUT+o0];
    float4 w2=*(const float4*)&Wt[(size_t)(k+2)*COUT+o0];
    float4 w3=*(const float4*)&Wt[(size_t)(k+3)*COUT+o0];
    #pragma unroll
    for (int fi=0;fi<FPT;fi++){
      float4 g=*(const float4*)&Gs[f0+fi][k];
      acc[fi].x=fmaf(g.x,w0.x,fmaf(g.y,w1.x,fmaf(g.z,w2.x,fmaf(g.w,w3.x,acc[fi].x))));
      acc[fi].y=fmaf(g.x,w0.y,fmaf(g.y,w1.y,fmaf(g.z,w2.y,fmaf(g.w,w3.y,acc[fi].y))));
      acc[fi].z=fmaf(g.x,w0.z,fmaf(g.y,w1.z,fmaf(g.z,w2.z,fmaf(g.w,w3.z,acc[fi].z))));
      acc[fi].w=fmaf(g.x,w0.w,fmaf(g.y,w1.w,fmaf(g.z,w2.w,fmaf(g.w,w3.w,acc[fi].w))));
    }
  }

  float4 rs={0,0,0,0}, rq={0,0,0,0};
  #pragma unroll
  for (int fi=0;fi<FPT;fi++){
    int fg=fbase+f0+fi;
    if (fg<F){
      *(float4*)&out[((size_t)b*F+fg)*COUT+o0]=acc[fi];
      if (STATS){
        float rx=relu_(acc[fi].x), ry=relu_(acc[fi].y);
        float rz=relu_(acc[fi].z), rw=relu_(acc[fi].w);
        rs.x+=rx; rs.y+=ry; rs.z+=rz; rs.w+=rw;
        rq.x+=rx*rx; rq.y+=ry*ry; rq.z+=rz*rz; rq.w+=rw*rw;
      }
    }
  }
  if (STATS){
    atomicAdd(&ls[o0+0],rs.x); atomicAdd(&ls[o0+1],rs.y);
    atomicAdd(&ls[o0+2],rs.z); atomicAdd(&ls[o0+3],rs.w);
    atomicAdd(&lq[o0+0],rq.x); atomicAdd(&lq[o0+1],rq.y);
    atomicAdd(&lq[o0+2],rq.z); atomicAdd(&lq[o0+3],rq.w);
    __syncthreads();
    int part=(blockIdx.y*gridDim.x+blockIdx.x)&(NPART-1);
    for (int i=t;i<COUT;i+=256){
      atomicAdd(&psum[(size_t)part*256+i], ls[i]);
      atomicAdd(&psum[(size_t)(NPART+part)*256+i], lq[i]);
    }
  }
}

template<int C>
__global__ __launch_bounds__(256) void add_relu_stats_kernel(
    const float* __restrict__ y0, float* __restrict__ z,
    float* __restrict__ psum, int n4)
{
  __shared__ float ls[C], lq[C];
  for (int i=threadIdx.x;i<C;i+=256){ ls[i]=0.f; lq[i]=0.f; }
  __syncthreads();
  int i0=blockIdx.x*256+threadIdx.x;
  int stride=gridDim.x*256;
  int c0=(i0*4)%C;
  float4 rs={0,0,0,0}, rq={0,0,0,0};
  for (int i=i0;i<n4;i+=stride){
    float4 a=*(const float4*)&y0[(size_t)i*4];
    float4 bq=*(const float4*)&z[(size_t)i*4];
    float4 v;
    v.x=relu_(a.x+bq.x); v.y=relu_(a.y+bq.y);
    v.z=relu_(a.z+bq.z); v.w=relu_(a.w+bq.w);
    *(float4*)&z[(size_t)i*4]=v;
    rs.x+=v.x; rs.y+=v.y; rs.z+=v.z; rs.w+=v.w;
    rq.x+=v.x*v.x; rq.y+=v.y*v.y; rq.z+=v.z*v.z; rq.w+=v.w*v.w;
  }
  atomicAdd(&ls[c0+0],rs.x); atomicAdd(&ls[c0+1],rs.y);
  atomicAdd(&ls[c0+2],rs.z); atomicAdd(&ls[c0+3],rs.w);
  atomicAdd(&lq[c0+0],rq.x); atomicAdd(&lq[c0+1],rq.y);
  atomicAdd(&lq[c0+2],rq.z); atomicAdd(&lq[c0+3],rq.w);
  __syncthreads();
  int part=blockIdx.x&(NPART-1);
  for (int i=threadIdx.x;i<C;i+=256){
    atomicAdd(&psum[(size_t)part*256+i],ls[i]);
    atomicAdd(&psum[(size_t)(NPART+part)*256+i],lq[i]);
  }
}

// pool with folded BN finalize: aS/dS computed from psum partials per block
__global__ __launch_bounds__(256) void pool_kernel(
    const float* __restrict__ z, const int* __restrict__ pl,
    const float* __restrict__ ps_in, const float* __restrict__ gamma,
    const float* __restrict__ beta,
    float* __restrict__ out, int C4, int F, int Fn, int n4, float invN)
{
  __shared__ float aS[256], dS[256];
  const int C=C4*4;
  const int t=threadIdx.x;
  if (t<C){
    float s=0.f,q=0.f;
    #pragma unroll 4
    for (int p=0;p<NPART;p++){ s+=ps_in[p*256+t]; q+=ps_in[(NPART+p)*256+t]; }
    float m=s*invN, v=q*invN-m*m;
    float ai=gamma[t]*rsqrtf(v+1e-5f);
    aS[t]=ai; dS[t]=beta[t]-m*ai;
  }
  __syncthreads();
  for (int i=blockIdx.x*256+t; i<n4; i+=gridDim.x*256){
    int c4=i%C4; int rest=i/C4; int p=rest%Fn; int b=rest/Fn;
    int p0=pl[p*3], p1=pl[p*3+1], p2=pl[p*3+2];
    float4 a4=*(const float4*)&aS[4*c4], d4=*(const float4*)&dS[4*c4];
    float4 v0=*(const float4*)&z[((size_t)b*F+p0)*C+4*c4];
    float4 v1=*(const float4*)&z[((size_t)b*F+p1)*C+4*c4];
    float4 v2=*(const float4*)&z[((size_t)b*F+p2)*C+4*c4];
    float4 r;
    r.x=(relu_(fmaf(v0.x,a4.x,d4.x))+relu_(fmaf(v1.x,a4.x,d4.x))+relu_(fmaf(v2.x,a4.x,d4.x)))*(1.f/3.f);
    r.y=(relu_(fmaf(v0.y,a4.y,d4.y))+relu_(fmaf(v1.y,a4.y,d4.y))+relu_(fmaf(v2.y,a4.y,d4.y)))*(1.f/3.f);
    r.z=(relu_(fmaf(v0.z,a4.z,d4.z))+relu_(fmaf(v1.z,a4.z,d4.z))+relu_(fmaf(v2.z,a4.z,d4.z)))*(1.f/3.f);
    r.w=(relu_(fmaf(v0.w,a4.w,d4.w))+relu_(fmaf(v1.w,a4.w,d4.w))+relu_(fmaf(v2.w,a4.w,d4.w)))*(1.f/3.f);
    *(float4*)&out[((size_t)b*Fn+p)*C+4*c4]=r;
  }
}

__global__ __launch_bounds__(256) void colsum_kernel(
    const float* __restrict__ x, float* __restrict__ bc, int F, int chunk)
{
  int b=blockIdx.y; int f0=blockIdx.x*chunk;
  int c=threadIdx.x;
  int fe=f0+chunk; if (fe>F) fe=F;
  float s=0.f;
  for (int f=f0;f<fe;f++) s+=x[((size_t)b*F+f)*256+c];
  atomicAdd(&bc[b*256+c], s);
}

__global__ __launch_bounds__(256) void head_kernel(
    const float* __restrict__ bc, const float* __restrict__ w1,
    const float* __restrict__ b1, const float* __restrict__ w2,
    const float* __restrict__ b2, float* __restrict__ outp, float invF)
{
  __shared__ float xm[8*256];
  __shared__ float h[8*128];
  int t=threadIdx.x;
  for (int i=t;i<2048;i+=256) xm[i]=bc[i]*invF;
  __syncthreads();
  #pragma unroll
  for (int r=0;r<4;r++){
    int idx=t+r*256; int b=idx>>7, j=idx&127;
    float s=b1[j];
    for (int c=0;c<256;c++) s=fmaf(xm[b*256+c],w1[j*256+c],s);
    h[idx]=relu_(s);
  }
  __syncthreads();
  if (t<8){
    float s=b2[0];
    for (int j=0;j<128;j++) s=fmaf(h[t*128+j],w2[j],s);
    outp[t]=1.f/(1.f+expf(-s));
  }
}

__global__ __launch_bounds__(256) void transpose_in_kernel(
    const float* __restrict__ x, float* __restrict__ xt, int F)
{
  int i=blockIdx.x*256+threadIdx.x;
  int total=8*9*F;
  if (i<total){ int f=i%F; int c=(i/F)%9; int b=i/(9*F);
    xt[((size_t)b*F+f)*9+c]=x[i]; }
}

__global__ __launch_bounds__(256) void transpose_w_kernel(
    const float* __restrict__ w, float* __restrict__ wt, int K, int COUT)
{
  int i=blockIdx.x*256+threadIdx.x;
  if (i<K*COUT){ int o=i/K, k=i-o*K; wt[(size_t)k*COUT+o]=w[i]; }
}

__global__ __launch_bounds__(256) void cvt_bf16_kernel(
    const float* __restrict__ w, u16* __restrict__ o, int n)
{
  int i=blockIdx.x*256+threadIdx.x;
  if (i<n) o[i]=f2bf(w[i]);
}

// ---------------------------------------------------------------------------

template<int CIN,int COUT,int WR,int NWR,bool BN,bool STATS>
static void launch_mconv(const float* xin, const int* nbr, const u16* wbf,
                         const float* ps_in, const float* gamma, const float* beta,
                         float* out, float* ps_out, int F, float invN,
                         hipStream_t stream)
{
  constexpr int T  = NWR*(COUT/64)*64;
  constexpr int BR = NWR*WR;
  int M = 8*F;
  mconv_kernel<CIN,COUT,WR,NWR,BN,STATS><<<M/BR, T, 0, stream>>>(
      xin,nbr,wbf,ps_in,gamma,beta,out,ps_out,F,invN);
}

extern "C" void kernel_launch(void* const* d_in, const int* in_sizes, int n_in,
                              void* d_out, int out_size, void* d_ws, size_t ws_size,
                              hipStream_t stream)
{
  const float* x    =(const float*)d_in[0];
  const int*  nbr0  =(const int*)d_in[1];
  const int*  pool0 =(const int*)d_in[2];
  const int*  nbr1  =(const int*)d_in[3];
  const int*  pool1 =(const int*)d_in[4];
  const int*  nbr2  =(const int*)d_in[5];
  const int*  pool2 =(const int*)d_in[6];
  const float* wc0  =(const float*)d_in[7];
  const float* ws0  =(const float*)d_in[8];
  const float* bng0 =(const float*)d_in[9];
  const float* bnb0 =(const float*)d_in[10];
  const float* ng0  =(const float*)d_in[11];
  const float* nb0  =(const float*)d_in[12];
  const float* wc1  =(const float*)d_in[13];
  const float* ws1  =(const float*)d_in[14];
  const float* bng1 =(const float*)d_in[15];
  const float* bnb1 =(const float*)d_in[16];
  const float* ng1  =(const float*)d_in[17];
  const float* nb1  =(const float*)d_in[18];
  const float* wc2  =(const float*)d_in[19];
  const float* ws2  =(const float*)d_in[20];
  const float* bng2 =(const float*)d_in[21];
  const float* bnb2 =(const float*)d_in[22];
  const float* ng2  =(const float*)d_in[23];
  const float* nb2  =(const float*)d_in[24];
  const float* fc1w =(const float*)d_in[25];
  const float* fc1b =(const float*)d_in[26];
  const float* fc2w =(const float*)d_in[27];
  const float* fc2b =(const float*)d_in[28];
  float* outp=(float*)d_out;

  char* base=(char*)d_ws;
  size_t off=0;
  auto alloc=[&](size_t nbytes)->void*{
    void* p=base+off; off=(off+nbytes+255)&~(size_t)255; return p; };

  float* psum0 =(float*)alloc((size_t)12*131072);
  float* bc    =(float*)alloc(8192);
  float* wt_wc0=(float*)alloc((size_t)36*64*4);
  u16*   bws0  =(u16*)alloc((size_t)3*16384*2);
  u16*   bwc1  =(u16*)alloc((size_t)32768*2);
  u16*   bws1  =(u16*)alloc((size_t)3*65536*2);
  u16*   bwc2  =(u16*)alloc((size_t)131072*2);
  u16*   bws2  =(u16*)alloc((size_t)3*262144*2);
  float* xT    =(float*)alloc((size_t)8*12000*9*4);
  float* B0    =(float*)alloc((size_t)49152000);
  float* B1    =(float*)alloc((size_t)49152000);
  float* B2    =(float*)alloc((size_t)49152000);
  if (off>ws_size) return;

  auto PS=[&](int i){ return psum0+(size_t)i*32768; };

  hipMemsetAsync(psum0,0,(size_t)12*131072+8192,stream);

  { int n=8*9*12000; transpose_in_kernel<<<(n+255)/256,256,0,stream>>>(x,xT,12000); }
  { int n=36*64; transpose_w_kernel<<<(n+255)/256,256,0,stream>>>(wc0,wt_wc0,36,64); }
  auto cv=[&](const float* w,u16* o,int n){
    cvt_bf16_kernel<<<(n+255)/256,256,0,stream>>>(w,o,n); };
  cv(ws0,bws0,3*16384);
  cv(wc1,bwc1,32768);
  cv(ws1,bws1,3*65536);
  cv(wc2,bwc2,131072);
  cv(ws2,bws2,3*262144);

  // -------- stage 0: F=12000, 9 -> 64 --------
  {
    const int F=12000; const float invN=1.f/(8.f*F);
    dim3 grid((F+TILE_F-1)/TILE_F, 8);
    conv_kernel<9,64,false,true><<<grid,256,0,stream>>>(xT,nbr0,wt_wc0,nullptr,nullptr,B0,PS(0),F);
    launch_mconv<64,64,32,2,true,true >(B0,nbr0,bws0,        PS(0),bng0,     bnb0,     B1,PS(1),F,invN,stream);
    launch_mconv<64,64,32,2,true,true >(B1,nbr0,bws0+16384,  PS(1),bng0+64,  bnb0+64,  B2,PS(2),F,invN,stream);
    launch_mconv<64,64,32,2,true,false>(B2,nbr0,bws0+32768,  PS(2),bng0+128, bnb0+128, B1,nullptr,F,invN,stream);
    int n4=8*F*64/4;
    int g=(n4+255)/256; if (g>2048) g=2048;
    add_relu_stats_kernel<64><<<g,256,0,stream>>>(B0,B1,PS(3),n4);
    int n4p=8*9000*16; int gp=(n4p+255)/256; if (gp>2048) gp=2048;
    pool_kernel<<<gp,256,0,stream>>>(B1,pool0,PS(3),ng0,nb0,B2,16,F,9000,n4p,invN);
  }
  // -------- stage 1: F=9000, 64 -> 128 --------
  {
    const int F=9000; const float invN=1.f/(8.f*F);
    launch_mconv<64,128,64,1,false,true >(B2,nbr1,bwc1,         nullptr,nullptr,  nullptr,  B0,PS(4),F,invN,stream);
    launch_mconv<128,128,64,1,true,true >(B0,nbr1,bws1,         PS(4),bng1,      bnb1,     B1,PS(5),F,invN,stream);
    launch_mconv<128,128,64,1,true,true >(B1,nbr1,bws1+65536,   PS(5),bng1+128,  bnb1+128, B2,PS(6),F,invN,stream);
    launch_mconv<128,128,64,1,true,false>(B2,nbr1,bws1+131072,  PS(6),bng1+256,  bnb1+256, B1,nullptr,F,invN,stream);
    int n4=8*F*128/4;
    int g=(n4+255)/256; if (g>2048) g=2048;
    add_relu_stats_kernel<128><<<g,256,0,stream>>>(B0,B1,PS(7),n4);
    int n4p=8*6000*32; int gp=(n4p+255)/256; if (gp>2048) gp=2048;
    pool_kernel<<<gp,256,0,stream>>>(B1,pool1,PS(7),ng1,nb1,B0,32,F,6000,n4p,invN);
  }
  // -------- stage 2: F=6000, 128 -> 256 --------
  {
    const int F=6000; const float invN=1.f/(8.f*F);
    launch_mconv<128,256,64,2,false,true >(B0,nbr2,bwc2,         nullptr,nullptr,  nullptr,  B1,PS(8),F,invN,stream);
    launch_mconv<256,256,64,2,true,true >(B1,nbr2,bws2,         PS(8), bng2,     bnb2,     B2,PS(9),F,invN,stream);
    launch_mconv<256,256,64,2,true,true >(B2,nbr2,bws2+262144,  PS(9), bng2+256, bnb2+256, B0,PS(10),F,invN,stream);
    launch_mconv<256,256,64,2,true,false>(B0,nbr2,bws2+524288,  PS(10),bng2+512, bnb2+512, B2,nullptr,F,invN,stream);
    int n4=8*F*256/4;
    int g=(n4+255)/256; if (g>2048) g=2048;
    add_relu_stats_kernel<256><<<g,256,0,stream>>>(B1,B2,PS(11),n4);
    int n4p=8*4000*64; int gp=(n4p+255)/256; if (gp>2048) gp=2048;
    pool_kernel<<<gp,256,0,stream>>>(B2,pool2,PS(11),ng2,nb2,B0,64,F,4000,n4p,invN);
    colsum_kernel<<<dim3(16,8),256,0,stream>>>(B0,bc,4000,250);
  }
  head_kernel<<<1,256,0,stream>>>(bc,fc1w,fc1b,fc2w,fc2b,outp,1.f/4000.f);
}

// Round 7
// 982.883 us; speedup vs baseline: 3.6508x; 1.1104x over previous
//
#include <hip/hip_runtime.h>
#include <math.h>

#define NPART 64
#define TILE_F 16

typedef unsigned short u16;
typedef __attribute__((ext_vector_type(8))) short short8;
typedef __attribute__((ext_vector_type(4))) float f32x4;

__device__ __forceinline__ float relu_(float v){ return fmaxf(v, 0.f); }

__device__ __forceinline__ u16 f2bf(float x){
  unsigned u = __float_as_uint(x);
  u = (u + 0x7fffu + ((u >> 16) & 1u)) >> 16;
  return (u16)u;
}

static __device__ __forceinline__ f32x4 mfma_bf16(short8 a, short8 b, f32x4 c){
  asm("v_mfma_f32_16x16x32_bf16 %0, %1, %2, %0" : "+v"(c) : "v"(a), "v"(b));
  return c;
}

// ---------------------------------------------------------------------------
// MFMA mesh-conv (round-3 verified structure), KSTEP=64, B prefetch one
// slice ahead, BN finalize folded into prologue.
//   out[r,o] = sum_k G[r,k] * W[o,k];  r = b*F+f, k = 4c+j
// ---------------------------------------------------------------------------
template<int CIN,int COUT,int WR,int NWR,bool BN,bool STATS>
__global__ __launch_bounds__(NWR*(COUT/64)*64) void mconv_kernel(
    const float* __restrict__ xin, const int* __restrict__ nbr,
    const u16* __restrict__ wbf,
    const float* __restrict__ ps_in, const float* __restrict__ gamma,
    const float* __restrict__ beta,
    float* __restrict__ out, float* __restrict__ psum,
    int F, float invN)
{
  constexpr int nWc = COUT/64;
  constexpr int T   = NWR*nWc*64;
  constexpr int BR  = NWR*WR;
  constexpr int K   = 4*CIN;
  constexpr int NSTEP = CIN/16;       // 16 channels (64 k) per step
  constexpr int ITEMS = (BR*4)/T;     // gather work items per thread
  constexpr int NRF   = WR/16;        // row fragments per wave

  __shared__ __align__(16) u16 Gs[2][BR*64];
  __shared__ float ls[STATS?COUT:1], lq[STATS?COUT:1];
  __shared__ float aS[BN?CIN:1], dS[BN?CIN:1];

  const int t=threadIdx.x, lane=t&63, wid=t>>6;
  const int wm=wid/nWc, wc=wid%nWc;
  const int l15=lane&15, kq=lane>>4;

  if (BN){
    for (int c=t;c<CIN;c+=T){
      float s=0.f,q=0.f;
      #pragma unroll 4
      for (int p=0;p<NPART;p++){ s+=ps_in[p*256+c]; q+=ps_in[(NPART+p)*256+c]; }
      float m=s*invN, v=q*invN-m*m;
      float ai=gamma[c]*rsqrtf(v+1e-5f);
      aS[c]=ai; dS[c]=beta[c]-m*ai;
    }
  }
  if (STATS){ for (int i=t;i<COUT;i+=T){ ls[i]=0.f; lq[i]=0.f; } }
  __syncthreads();

  // ---- gather pointers (fixed rows/channel-quads per thread) ----
  const float *P0[ITEMS],*P1[ITEMS],*P2[ITEMS],*P3[ITEMS];
  #pragma unroll
  for (int i=0;i<ITEMS;i++){
    int idx=i*T+t, gr=idx>>2, c4q=idx&3;
    int rg=blockIdx.x*BR+gr;
    int b=rg/F, f=rg-b*F;
    int i1=nbr[f*3+0], i2=nbr[f*3+1], i3=nbr[f*3+2];
    const float* xb=xin+(size_t)b*F*CIN+c4q*4;
    P0[i]=xb+(size_t)f *CIN; P1[i]=xb+(size_t)i1*CIN;
    P2[i]=xb+(size_t)i2*CIN; P3[i]=xb+(size_t)i3*CIN;
  }

  const u16* wp = wbf + (size_t)(wc*64+l15)*K + kq*8;
  auto BLD=[&](int cg,int j)->short8{
    return *(const short8*)(wp + (size_t)cg*16*K + (size_t)j*32);
  };
  auto ADS=[&](int pb,int rr,int h)->short8{
    int r=wm*WR+rr*16+l15;
    int sl=h*4+kq;
    return *(const short8*)&Gs[pb][(size_t)r*64 + (size_t)((sl^(r&7))*8)];
  };
  auto GLD=[&](int s,float4 (&g)[ITEMS][4]){
    #pragma unroll
    for (int i=0;i<ITEMS;i++){
      g[i][0]=*(const float4*)(P0[i]+s*16);
      g[i][1]=*(const float4*)(P1[i]+s*16);
      g[i][2]=*(const float4*)(P2[i]+s*16);
      g[i][3]=*(const float4*)(P3[i]+s*16);
    }
  };
  auto BLDW=[&](int pb,int s,float4 (&g)[ITEMS][4]){
    #pragma unroll
    for (int i=0;i<ITEMS;i++){
      int idx=i*T+t, gr=idx>>2, c4q=idx&3;
      float4 S=g[i][0],N1=g[i][1],N2=g[i][2],N3=g[i][3];
      if (BN){
        float4 a4=*(const float4*)&aS[s*16+c4q*4];
        float4 d4=*(const float4*)&dS[s*16+c4q*4];
        S.x =fmaf(relu_(S.x ),a4.x,d4.x); S.y =fmaf(relu_(S.y ),a4.y,d4.y);
        S.z =fmaf(relu_(S.z ),a4.z,d4.z); S.w =fmaf(relu_(S.w ),a4.w,d4.w);
        N1.x=fmaf(relu_(N1.x),a4.x,d4.x); N1.y=fmaf(relu_(N1.y),a4.y,d4.y);
        N1.z=fmaf(relu_(N1.z),a4.z,d4.z); N1.w=fmaf(relu_(N1.w),a4.w,d4.w);
        N2.x=fmaf(relu_(N2.x),a4.x,d4.x); N2.y=fmaf(relu_(N2.y),a4.y,d4.y);
        N2.z=fmaf(relu_(N2.z),a4.z,d4.z); N2.w=fmaf(relu_(N2.w),a4.w,d4.w);
        N3.x=fmaf(relu_(N3.x),a4.x,d4.x); N3.y=fmaf(relu_(N3.y),a4.y,d4.y);
        N3.z=fmaf(relu_(N3.z),a4.z,d4.z); N3.w=fmaf(relu_(N3.w),a4.w,d4.w);
      }
      short8 lo,hi;
      #define FEAT(dst,i0,sv,av,bv,cv) \
        dst[i0+0]=(short)f2bf(sv); \
        dst[i0+1]=(short)f2bf(av+bv+cv); \
        dst[i0+2]=(short)f2bf(fabsf(av-bv)+fabsf(bv-cv)+fabsf(cv-av)); \
        dst[i0+3]=(short)f2bf(fmaxf(fmaxf(av,bv),cv));
      FEAT(lo,0,S.x,N1.x,N2.x,N3.x)
      FEAT(lo,4,S.y,N1.y,N2.y,N3.y)
      FEAT(hi,0,S.z,N1.z,N2.z,N3.z)
      FEAT(hi,4,S.w,N1.w,N2.w,N3.w)
      #undef FEAT
      u16* rowp=&Gs[pb][(size_t)gr*64];
      *(short8*)&rowp[(size_t)(((2*c4q  )^(gr&7))*8)]=lo;
      *(short8*)&rowp[(size_t)(((2*c4q+1)^(gr&7))*8)]=hi;
    }
  };

  f32x4 acc[NRF][4];
  #pragma unroll
  for (int rr=0;rr<NRF;rr++)
    #pragma unroll
    for (int cg=0;cg<4;cg++){ f32x4 z={0.f,0.f,0.f,0.f}; acc[rr][cg]=z; }

  short8 B0[4],B1[4];
  #pragma unroll
  for (int cg=0;cg<4;cg++) B0[cg]=BLD(cg,0);
  #pragma unroll
  for (int cg=0;cg<4;cg++) B1[cg]=BLD(cg,1);

  { float4 g0[ITEMS][4]; GLD(0,g0); BLDW(0,0,g0); }
  __syncthreads();

  #pragma unroll 2
  for (int s=0;s<NSTEP;s++){
    const int pb=s&1;
    float4 g[ITEMS][4];
    if (s+1<NSTEP) GLD(s+1,g);               // issue gathers for next step
    short8 A[NRF];
    #pragma unroll
    for (int rr=0;rr<NRF;rr++) A[rr]=ADS(pb,rr,0);
    #pragma unroll
    for (int rr=0;rr<NRF;rr++)
      #pragma unroll
      for (int cg=0;cg<4;cg++) acc[rr][cg]=mfma_bf16(A[rr],B0[cg],acc[rr][cg]);
    if (s+1<NSTEP){
      #pragma unroll
      for (int cg=0;cg<4;cg++) B0[cg]=BLD(cg,2*(s+1));   // prefetch next slice
    }
    #pragma unroll
    for (int rr=0;rr<NRF;rr++) A[rr]=ADS(pb,rr,1);
    #pragma unroll
    for (int rr=0;rr<NRF;rr++)
      #pragma unroll
      for (int cg=0;cg<4;cg++) acc[rr][cg]=mfma_bf16(A[rr],B1[cg],acc[rr][cg]);
    if (s+1<NSTEP){
      #pragma unroll
      for (int cg=0;cg<4;cg++) B1[cg]=BLD(cg,2*(s+1)+1);
      BLDW(pb^1,s+1,g);                      // features -> other buffer
    }
    __syncthreads();
  }

  // ---- epilogue: store + relu stats ----
  #pragma unroll
  for (int cg=0;cg<4;cg++){
    const int col=wc*64+cg*16+l15;
    float rs=0.f,rq=0.f;
    #pragma unroll
    for (int rr=0;rr<NRF;rr++){
      const size_t rbase=(size_t)blockIdx.x*BR + wm*WR + rr*16 + kq*4;
      #pragma unroll
      for (int q=0;q<4;q++){
        float v=acc[rr][cg][q];
        out[(rbase+q)*COUT+col]=v;
        if (STATS){ float rv=relu_(v); rs+=rv; rq+=rv*rv; }
      }
    }
    if (STATS){ atomicAdd(&ls[col],rs); atomicAdd(&lq[col],rq); }
  }
  if (STATS){
    __syncthreads();
    const int part=blockIdx.x&(NPART-1);
    for (int i=t;i<COUT;i+=T){
      atomicAdd(&psum[(size_t)part*256+i],ls[i]);
      atomicAdd(&psum[(size_t)(NPART+part)*256+i],lq[i]);
    }
  }
}

// ---------------------------------------------------------------------------
// fp32 conv path (tiny 9->64 conv only)
// ---------------------------------------------------------------------------
template<int CIN,int COUT,bool BN,bool STATS>
__global__ __launch_bounds__(256) void conv_kernel(
    const float* __restrict__ xin, const int* __restrict__ nbr,
    const float* __restrict__ Wt, const float* __restrict__ bn_a,
    const float* __restrict__ bn_d,
    float* __restrict__ out, float* __restrict__ psum, int F)
{
  constexpr int K = 4*CIN;
  constexpr int ROWLEN = K + 4;
  __shared__ float Gs[TILE_F][ROWLEN];
  __shared__ int   nI[TILE_F*3];
  __shared__ float ls[STATS?COUT:1];
  __shared__ float lq[STATS?COUT:1];
  const int t = threadIdx.x;
  const int fbase = blockIdx.x*TILE_F;
  const int b = blockIdx.y;
  const float* __restrict__ xb = xin + (size_t)b*F*CIN;

  if (t < TILE_F*3){ int fi=t/3, j=t-fi*3; int fg=fbase+fi; nI[t]=(fg<F)?nbr[fg*3+j]:0; }
  if (STATS){ for (int i=t;i<COUT;i+=256){ ls[i]=0.f; lq[i]=0.f; } }
  __syncthreads();

  for (int idx=t; idx<TILE_F*CIN; idx+=256){
    int fi=idx/CIN, c=idx-fi*CIN;
    int fg=fbase+fi;
    float* dst=&Gs[fi][4*c];
    if (fg<F){
      int i1=nI[fi*3], i2=nI[fi*3+1], i3=nI[fi*3+2];
      float s =xb[(size_t)fg*CIN+c];
      float v1=xb[(size_t)i1*CIN+c];
      float v2=xb[(size_t)i2*CIN+c];
      float v3=xb[(size_t)i3*CIN+c];
      if (BN){ float a=bn_a[c], dd=bn_d[c];
        s=fmaf(relu_(s),a,dd); v1=fmaf(relu_(v1),a,dd);
        v2=fmaf(relu_(v2),a,dd); v3=fmaf(relu_(v3),a,dd); }
      dst[0]=s; dst[1]=v1+v2+v3;
      dst[2]=fabsf(v1-v2)+fabsf(v2-v3)+fabsf(v3-v1);
      dst[3]=fmaxf(fmaxf(v1,v2),v3);
    } else { dst[0]=0.f;dst[1]=0.f;dst[2]=0.f;dst[3]=0.f; }
  }
  __syncthreads();

  constexpr int OQ=COUT/4;
  constexpr int R=256/OQ;
  constexpr int FPT=TILE_F/R;
  const int col=t%OQ, row=t/OQ;
  const int o0=col*4, f0=row*FPT;
  float4 acc[FPT];
  #pragma unroll
  for (int fi=0;fi<FPT;fi++){ acc[fi].x=0.f;acc[fi].y=0.f;acc[fi].z=0.f;acc[fi].w=0.f; }

  for (int k=0;k<K;k+=4){
    float4 w0=*(const float4*)&Wt[(size_t)(k+0)*COUT+o0];
    float4 w1=*(const float4*)&Wt[(size_t)(k+1)*COUT+o0];
    float4 w2=*(const float4*)&Wt[(size_t)(k+2)*COUT+o0];
    float4 w3=*(const float4*)&Wt[(size_t)(k+3)*COUT+o0];
    #pragma unroll
    for (int fi=0;fi<FPT;fi++){
      float4 g=*(const float4*)&Gs[f0+fi][k];
      acc[fi].x=fmaf(g.x,w0.x,fmaf(g.y,w1.x,fmaf(g.z,w2.x,fmaf(g.w,w3.x,acc[fi].x))));
      acc[fi].y=fmaf(g.x,w0.y,fmaf(g.y,w1.y,fmaf(g.z,w2.y,fmaf(g.w,w3.y,acc[fi].y))));
      acc[fi].z=fmaf(g.x,w0.z,fmaf(g.y,w1.z,fmaf(g.z,w2.z,fmaf(g.w,w3.z,acc[fi].z))));
      acc[fi].w=fmaf(g.x,w0.w,fmaf(g.y,w1.w,fmaf(g.z,w2.w,fmaf(g.w,w3.w,acc[fi].w))));
    }
  }

  float4 rs={0,0,0,0}, rq={0,0,0,0};
  #pragma unroll
  for (int fi=0;fi<FPT;fi++){
    int fg=fbase+f0+fi;
    if (fg<F){
      *(float4*)&out[((size_t)b*F+fg)*COUT+o0]=acc[fi];
      if (STATS){
        float rx=relu_(acc[fi].x), ry=relu_(acc[fi].y);
        float rz=relu_(acc[fi].z), rw=relu_(acc[fi].w);
        rs.x+=rx; rs.y+=ry; rs.z+=rz; rs.w+=rw;
        rq.x+=rx*rx; rq.y+=ry*ry; rq.z+=rz*rz; rq.w+=rw*rw;
      }
    }
  }
  if (STATS){
    atomicAdd(&ls[o0+0],rs.x); atomicAdd(&ls[o0+1],rs.y);
    atomicAdd(&ls[o0+2],rs.z); atomicAdd(&ls[o0+3],rs.w);
    atomicAdd(&lq[o0+0],rq.x); atomicAdd(&lq[o0+1],rq.y);
    atomicAdd(&lq[o0+2],rq.z); atomicAdd(&lq[o0+3],rq.w);
    __syncthreads();
    int part=(blockIdx.y*gridDim.x+blockIdx.x)&(NPART-1);
    for (int i=t;i<COUT;i+=256){
      atomicAdd(&psum[(size_t)part*256+i], ls[i]);
      atomicAdd(&psum[(size_t)(NPART+part)*256+i], lq[i]);
    }
  }
}

template<int C>
__global__ __launch_bounds__(256) void add_relu_stats_kernel(
    const float* __restrict__ y0, float* __restrict__ z,
    float* __restrict__ psum, int n4)
{
  __shared__ float ls[C], lq[C];
  for (int i=threadIdx.x;i<C;i+=256){ ls[i]=0.f; lq[i]=0.f; }
  __syncthreads();
  int i0=blockIdx.x*256+threadIdx.x;
  int stride=gridDim.x*256;
  int c0=(i0*4)%C;
  float4 rs={0,0,0,0}, rq={0,0,0,0};
  for (int i=i0;i<n4;i+=stride){
    float4 a=*(const float4*)&y0[(size_t)i*4];
    float4 bq=*(const float4*)&z[(size_t)i*4];
    float4 v;
    v.x=relu_(a.x+bq.x); v.y=relu_(a.y+bq.y);
    v.z=relu_(a.z+bq.z); v.w=relu_(a.w+bq.w);
    *(float4*)&z[(size_t)i*4]=v;
    rs.x+=v.x; rs.y+=v.y; rs.z+=v.z; rs.w+=v.w;
    rq.x+=v.x*v.x; rq.y+=v.y*v.y; rq.z+=v.z*v.z; rq.w+=v.w*v.w;
  }
  atomicAdd(&ls[c0+0],rs.x); atomicAdd(&ls[c0+1],rs.y);
  atomicAdd(&ls[c0+2],rs.z); atomicAdd(&ls[c0+3],rs.w);
  atomicAdd(&lq[c0+0],rq.x); atomicAdd(&lq[c0+1],rq.y);
  atomicAdd(&lq[c0+2],rq.z); atomicAdd(&lq[c0+3],rq.w);
  __syncthreads();
  int part=blockIdx.x&(NPART-1);
  for (int i=threadIdx.x;i<C;i+=256){
    atomicAdd(&psum[(size_t)part*256+i],ls[i]);
    atomicAdd(&psum[(size_t)(NPART+part)*256+i],lq[i]);
  }
}

// pool with folded BN finalize: aS/dS computed from psum partials per block
__global__ __launch_bounds__(256) void pool_kernel(
    const float* __restrict__ z, const int* __restrict__ pl,
    const float* __restrict__ ps_in, const float* __restrict__ gamma,
    const float* __restrict__ beta,
    float* __restrict__ out, int C4, int F, int Fn, int n4, float invN)
{
  __shared__ float aS[256], dS[256];
  const int C=C4*4;
  const int t=threadIdx.x;
  if (t<C){
    float s=0.f,q=0.f;
    #pragma unroll 4
    for (int p=0;p<NPART;p++){ s+=ps_in[p*256+t]; q+=ps_in[(NPART+p)*256+t]; }
    float m=s*invN, v=q*invN-m*m;
    float ai=gamma[t]*rsqrtf(v+1e-5f);
    aS[t]=ai; dS[t]=beta[t]-m*ai;
  }
  __syncthreads();
  for (int i=blockIdx.x*256+t; i<n4; i+=gridDim.x*256){
    int c4=i%C4; int rest=i/C4; int p=rest%Fn; int b=rest/Fn;
    int p0=pl[p*3], p1=pl[p*3+1], p2=pl[p*3+2];
    float4 a4=*(const float4*)&aS[4*c4], d4=*(const float4*)&dS[4*c4];
    float4 v0=*(const float4*)&z[((size_t)b*F+p0)*C+4*c4];
    float4 v1=*(const float4*)&z[((size_t)b*F+p1)*C+4*c4];
    float4 v2=*(const float4*)&z[((size_t)b*F+p2)*C+4*c4];
    float4 r;
    r.x=(relu_(fmaf(v0.x,a4.x,d4.x))+relu_(fmaf(v1.x,a4.x,d4.x))+relu_(fmaf(v2.x,a4.x,d4.x)))*(1.f/3.f);
    r.y=(relu_(fmaf(v0.y,a4.y,d4.y))+relu_(fmaf(v1.y,a4.y,d4.y))+relu_(fmaf(v2.y,a4.y,d4.y)))*(1.f/3.f);
    r.z=(relu_(fmaf(v0.z,a4.z,d4.z))+relu_(fmaf(v1.z,a4.z,d4.z))+relu_(fmaf(v2.z,a4.z,d4.z)))*(1.f/3.f);
    r.w=(relu_(fmaf(v0.w,a4.w,d4.w))+relu_(fmaf(v1.w,a4.w,d4.w))+relu_(fmaf(v2.w,a4.w,d4.w)))*(1.f/3.f);
    *(float4*)&out[((size_t)b*Fn+p)*C+4*c4]=r;
  }
}

__global__ __launch_bounds__(256) void colsum_kernel(
    const float* __restrict__ x, float* __restrict__ bc, int F, int chunk)
{
  int b=blockIdx.y; int f0=blockIdx.x*chunk;
  int c=threadIdx.x;
  int fe=f0+chunk; if (fe>F) fe=F;
  float s=0.f;
  for (int f=f0;f<fe;f++) s+=x[((size_t)b*F+f)*256+c];
  atomicAdd(&bc[b*256+c], s);
}

__global__ __launch_bounds__(256) void head_kernel(
    const float* __restrict__ bc, const float* __restrict__ w1,
    const float* __restrict__ b1, const float* __restrict__ w2,
    const float* __restrict__ b2, float* __restrict__ outp, float invF)
{
  __shared__ float xm[8*256];
  __shared__ float h[8*128];
  int t=threadIdx.x;
  for (int i=t;i<2048;i+=256) xm[i]=bc[i]*invF;
  __syncthreads();
  #pragma unroll
  for (int r=0;r<4;r++){
    int idx=t+r*256; int b=idx>>7, j=idx&127;
    float s=b1[j];
    for (int c=0;c<256;c++) s=fmaf(xm[b*256+c],w1[j*256+c],s);
    h[idx]=relu_(s);
  }
  __syncthreads();
  if (t<8){
    float s=b2[0];
    for (int j=0;j<128;j++) s=fmaf(h[t*128+j],w2[j],s);
    outp[t]=1.f/(1.f+expf(-s));
  }
}

__global__ __launch_bounds__(256) void transpose_in_kernel(
    const float* __restrict__ x, float* __restrict__ xt, int F)
{
  int i=blockIdx.x*256+threadIdx.x;
  int total=8*9*F;
  if (i<total){ int f=i%F; int c=(i/F)%9; int b=i/(9*F);
    xt[((size_t)b*F+f)*9+c]=x[i]; }
}

__global__ __launch_bounds__(256) void transpose_w_kernel(
    const float* __restrict__ w, float* __restrict__ wt, int K, int COUT)
{
  int i=blockIdx.x*256+threadIdx.x;
  if (i<K*COUT){ int o=i/K, k=i-o*K; wt[(size_t)k*COUT+o]=w[i]; }
}

__global__ __launch_bounds__(256) void cvt_bf16_kernel(
    const float* __restrict__ w, u16* __restrict__ o, int n)
{
  int i=blockIdx.x*256+threadIdx.x;
  if (i<n) o[i]=f2bf(w[i]);
}

// ---------------------------------------------------------------------------

template<int CIN,int COUT,int WR,int NWR,bool BN,bool STATS>
static void launch_mconv(const float* xin, const int* nbr, const u16* wbf,
                         const float* ps_in, const float* gamma, const float* beta,
                         float* out, float* ps_out, int F, float invN,
                         hipStream_t stream)
{
  constexpr int T  = NWR*(COUT/64)*64;
  constexpr int BR = NWR*WR;
  int M = 8*F;
  mconv_kernel<CIN,COUT,WR,NWR,BN,STATS><<<M/BR, T, 0, stream>>>(
      xin,nbr,wbf,ps_in,gamma,beta,out,ps_out,F,invN);
}

extern "C" void kernel_launch(void* const* d_in, const int* in_sizes, int n_in,
                              void* d_out, int out_size, void* d_ws, size_t ws_size,
                              hipStream_t stream)
{
  const float* x    =(const float*)d_in[0];
  const int*  nbr0  =(const int*)d_in[1];
  const int*  pool0 =(const int*)d_in[2];
  const int*  nbr1  =(const int*)d_in[3];
  const int*  pool1 =(const int*)d_in[4];
  const int*  nbr2  =(const int*)d_in[5];
  const int*  pool2 =(const int*)d_in[6];
  const float* wc0  =(const float*)d_in[7];
  const float* ws0  =(const float*)d_in[8];
  const float* bng0 =(const float*)d_in[9];
  const float* bnb0 =(const float*)d_in[10];
  const float* ng0  =(const float*)d_in[11];
  const float* nb0  =(const float*)d_in[12];
  const float* wc1  =(const float*)d_in[13];
  const float* ws1  =(const float*)d_in[14];
  const float* bng1 =(const float*)d_in[15];
  const float* bnb1 =(const float*)d_in[16];
  const float* ng1  =(const float*)d_in[17];
  const float* nb1  =(const float*)d_in[18];
  const float* wc2  =(const float*)d_in[19];
  const float* ws2  =(const float*)d_in[20];
  const float* bng2 =(const float*)d_in[21];
  const float* bnb2 =(const float*)d_in[22];
  const float* ng2  =(const float*)d_in[23];
  const float* nb2  =(const float*)d_in[24];
  const float* fc1w =(const float*)d_in[25];
  const float* fc1b =(const float*)d_in[26];
  const float* fc2w =(const float*)d_in[27];
  const float* fc2b =(const float*)d_in[28];
  float* outp=(float*)d_out;

  char* base=(char*)d_ws;
  size_t off=0;
  auto alloc=[&](size_t nbytes)->void*{
    void* p=base+off; off=(off+nbytes+255)&~(size_t)255; return p; };

  float* psum0 =(float*)alloc((size_t)12*131072);
  float* bc    =(float*)alloc(8192);
  float* wt_wc0=(float*)alloc((size_t)36*64*4);
  u16*   bws0  =(u16*)alloc((size_t)3*16384*2);
  u16*   bwc1  =(u16*)alloc((size_t)32768*2);
  u16*   bws1  =(u16*)alloc((size_t)3*65536*2);
  u16*   bwc2  =(u16*)alloc((size_t)131072*2);
  u16*   bws2  =(u16*)alloc((size_t)3*262144*2);
  float* xT    =(float*)alloc((size_t)8*12000*9*4);
  float* B0    =(float*)alloc((size_t)49152000);
  float* B1    =(float*)alloc((size_t)49152000);
  float* B2    =(float*)alloc((size_t)49152000);
  if (off>ws_size) return;

  auto PS=[&](int i){ return psum0+(size_t)i*32768; };

  hipMemsetAsync(psum0,0,(size_t)12*131072+8192,stream);

  { int n=8*9*12000; transpose_in_kernel<<<(n+255)/256,256,0,stream>>>(x,xT,12000); }
  { int n=36*64; transpose_w_kernel<<<(n+255)/256,256,0,stream>>>(wc0,wt_wc0,36,64); }
  auto cv=[&](const float* w,u16* o,int n){
    cvt_bf16_kernel<<<(n+255)/256,256,0,stream>>>(w,o,n); };
  cv(ws0,bws0,3*16384);
  cv(wc1,bwc1,32768);
  cv(ws1,bws1,3*65536);
  cv(wc2,bwc2,131072);
  cv(ws2,bws2,3*262144);

  // -------- stage 0: F=12000, 9 -> 64 --------
  {
    const int F=12000; const float invN=1.f/(8.f*F);
    dim3 grid((F+TILE_F-1)/TILE_F, 8);
    conv_kernel<9,64,false,true><<<grid,256,0,stream>>>(xT,nbr0,wt_wc0,nullptr,nullptr,B0,PS(0),F);
    launch_mconv<64,64,32,2,true,true >(B0,nbr0,bws0,        PS(0),bng0,     bnb0,     B1,PS(1),F,invN,stream);
    launch_mconv<64,64,32,2,true,true >(B1,nbr0,bws0+16384,  PS(1),bng0+64,  bnb0+64,  B2,PS(2),F,invN,stream);
    launch_mconv<64,64,32,2,true,false>(B2,nbr0,bws0+32768,  PS(2),bng0+128, bnb0+128, B1,nullptr,F,invN,stream);
    int n4=8*F*64/4;
    int g=(n4+255)/256; if (g>2048) g=2048;
    add_relu_stats_kernel<64><<<g,256,0,stream>>>(B0,B1,PS(3),n4);
    int n4p=8*9000*16; int gp=(n4p+255)/256; if (gp>2048) gp=2048;
    pool_kernel<<<gp,256,0,stream>>>(B1,pool0,PS(3),ng0,nb0,B2,16,F,9000,n4p,invN);
  }
  // -------- stage 1: F=9000, 64 -> 128 --------
  {
    const int F=9000; const float invN=1.f/(8.f*F);
    launch_mconv<64,128,64,1,false,true >(B2,nbr1,bwc1,         nullptr,nullptr,  nullptr,  B0,PS(4),F,invN,stream);
    launch_mconv<128,128,64,1,true,true >(B0,nbr1,bws1,         PS(4),bng1,      bnb1,     B1,PS(5),F,invN,stream);
    launch_mconv<128,128,64,1,true,true >(B1,nbr1,bws1+65536,   PS(5),bng1+128,  bnb1+128, B2,PS(6),F,invN,stream);
    launch_mconv<128,128,64,1,true,false>(B2,nbr1,bws1+131072,  PS(6),bng1+256,  bnb1+256, B1,nullptr,F,invN,stream);
    int n4=8*F*128/4;
    int g=(n4+255)/256; if (g>2048) g=2048;
    add_relu_stats_kernel<128><<<g,256,0,stream>>>(B0,B1,PS(7),n4);
    int n4p=8*6000*32; int gp=(n4p+255)/256; if (gp>2048) gp=2048;
    pool_kernel<<<gp,256,0,stream>>>(B1,pool1,PS(7),ng1,nb1,B0,32,F,6000,n4p,invN);
  }
  // -------- stage 2: F=6000, 128 -> 256 --------
  // NWR=1 -> 256-thread blocks, BR=64, grid 750 (was 375 @ 512 threads):
  // doubles resident-block balance across 256 CUs, LDS 36->20 KB.
  {
    const int F=6000; const float invN=1.f/(8.f*F);
    launch_mconv<128,256,64,1,false,true >(B0,nbr2,bwc2,         nullptr,nullptr,  nullptr,  B1,PS(8),F,invN,stream);
    launch_mconv<256,256,64,1,true,true >(B1,nbr2,bws2,         PS(8), bng2,     bnb2,     B2,PS(9),F,invN,stream);
    launch_mconv<256,256,64,1,true,true >(B2,nbr2,bws2+262144,  PS(9), bng2+256, bnb2+256, B0,PS(10),F,invN,stream);
    launch_mconv<256,256,64,1,true,false>(B0,nbr2,bws2+524288,  PS(10),bng2+512, bnb2+512, B2,nullptr,F,invN,stream);
    int n4=8*F*256/4;
    int g=(n4+255)/256; if (g>2048) g=2048;
    add_relu_stats_kernel<256><<<g,256,0,stream>>>(B1,B2,PS(11),n4);
    int n4p=8*4000*64; int gp=(n4p+255)/256; if (gp>2048) gp=2048;
    pool_kernel<<<gp,256,0,stream>>>(B2,pool2,PS(11),ng2,nb2,B0,64,F,4000,n4p,invN);
    colsum_kernel<<<dim3(16,8),256,0,stream>>>(B0,bc,4000,250);
  }
  head_kernel<<<1,256,0,stream>>>(bc,fc1w,fc1b,fc2w,fc2b,outp,1.f/4000.f);
}

// Round 9
// 965.910 us; speedup vs baseline: 3.7150x; 1.0176x over previous
//
#include <hip/hip_runtime.h>
#include <math.h>

#define NPART 64
#define TILE_F 16

typedef unsigned short u16;
typedef __attribute__((ext_vector_type(8))) short short8;
typedef __attribute__((ext_vector_type(4))) float f32x4;

__device__ __forceinline__ float relu_(float v){ return fmaxf(v, 0.f); }

__device__ __forceinline__ u16 f2bf(float x){
  unsigned u = __float_as_uint(x);
  u = (u + 0x7fffu + ((u >> 16) & 1u)) >> 16;
  return (u16)u;
}

static __device__ __forceinline__ f32x4 mfma_bf16(short8 a, short8 b, f32x4 c){
  asm("v_mfma_f32_16x16x32_bf16 %0, %1, %2, %0" : "+v"(c) : "v"(a), "v"(b));
  return c;
}

// ---------------------------------------------------------------------------
// MFMA mesh-conv (round-3/7 verified structure), KSTEP=64.
// 2-step-ahead gather prefetch (gA/gB named register sets, manual 2x unroll),
// B-slice prefetch, BN finalize folded into prologue,
// optional fused residual relu(y + res) epilogue (replaces add_relu_stats).
//   out[r,o] = sum_k G[r,k] * W[o,k];  r = b*F+f, k = 4c+j
// ---------------------------------------------------------------------------
template<int CIN,int COUT,int WR,int NWR,bool BN,bool STATS,bool RES>
__global__ __launch_bounds__(NWR*(COUT/64)*64) void mconv_kernel(
    const float* __restrict__ xin, const int* __restrict__ nbr,
    const u16* __restrict__ wbf,
    const float* __restrict__ ps_in, const float* __restrict__ gamma,
    const float* __restrict__ beta, const float* __restrict__ res,
    float* __restrict__ out, float* __restrict__ psum,
    int F, float invN)
{
  constexpr int nWc = COUT/64;
  constexpr int T   = NWR*nWc*64;
  constexpr int BR  = NWR*WR;
  constexpr int K   = 4*CIN;
  constexpr int NSTEP = CIN/16;       // 16 channels (64 k) per step; even >=4
  constexpr int ITEMS = (BR*4)/T;     // gather work items per thread
  constexpr int NRF   = WR/16;        // row fragments per wave

  __shared__ __align__(16) u16 Gs[2][BR*64];
  __shared__ float ls[STATS?COUT:1], lq[STATS?COUT:1];
  __shared__ float aS[BN?CIN:1], dS[BN?CIN:1];

  const int t=threadIdx.x, lane=t&63, wid=t>>6;
  const int wm=wid/nWc, wc=wid%nWc;
  const int l15=lane&15, kq=lane>>4;

  if (BN){
    for (int c=t;c<CIN;c+=T){
      float s=0.f,q=0.f;
      #pragma unroll 4
      for (int p=0;p<NPART;p++){ s+=ps_in[p*256+c]; q+=ps_in[(NPART+p)*256+c]; }
      float m=s*invN, v=q*invN-m*m;
      float ai=gamma[c]*rsqrtf(v+1e-5f);
      aS[c]=ai; dS[c]=beta[c]-m*ai;
    }
  }
  if (STATS){ for (int i=t;i<COUT;i+=T){ ls[i]=0.f; lq[i]=0.f; } }
  __syncthreads();

  // ---- gather pointers (fixed rows/channel-quads per thread) ----
  const float *P0[ITEMS],*P1[ITEMS],*P2[ITEMS],*P3[ITEMS];
  #pragma unroll
  for (int i=0;i<ITEMS;i++){
    int idx=i*T+t, gr=idx>>2, c4q=idx&3;
    int rg=blockIdx.x*BR+gr;
    int b=rg/F, f=rg-b*F;
    int i1=nbr[f*3+0], i2=nbr[f*3+1], i3=nbr[f*3+2];
    const float* xb=xin+(size_t)b*F*CIN+c4q*4;
    P0[i]=xb+(size_t)f *CIN; P1[i]=xb+(size_t)i1*CIN;
    P2[i]=xb+(size_t)i2*CIN; P3[i]=xb+(size_t)i3*CIN;
  }

  const u16* wp = wbf + (size_t)(wc*64+l15)*K + kq*8;
  auto BLD=[&](int cg,int j)->short8{
    return *(const short8*)(wp + (size_t)cg*16*K + (size_t)j*32);
  };
  auto ADS=[&](int pb,int rr,int h)->short8{
    int r=wm*WR+rr*16+l15;
    int sl=h*4+kq;
    return *(const short8*)&Gs[pb][(size_t)r*64 + (size_t)((sl^(r&7))*8)];
  };
  auto GLD=[&](int s,float4 (&g)[ITEMS][4]){
    #pragma unroll
    for (int i=0;i<ITEMS;i++){
      g[i][0]=*(const float4*)(P0[i]+s*16);
      g[i][1]=*(const float4*)(P1[i]+s*16);
      g[i][2]=*(const float4*)(P2[i]+s*16);
      g[i][3]=*(const float4*)(P3[i]+s*16);
    }
  };
  auto BLDW=[&](int pb,int s,float4 (&g)[ITEMS][4]){
    #pragma unroll
    for (int i=0;i<ITEMS;i++){
      int idx=i*T+t, gr=idx>>2, c4q=idx&3;
      float4 S=g[i][0],N1=g[i][1],N2=g[i][2],N3=g[i][3];
      if (BN){
        float4 a4=*(const float4*)&aS[s*16+c4q*4];
        float4 d4=*(const float4*)&dS[s*16+c4q*4];
        S.x =fmaf(relu_(S.x ),a4.x,d4.x); S.y =fmaf(relu_(S.y ),a4.y,d4.y);
        S.z =fmaf(relu_(S.z ),a4.z,d4.z); S.w =fmaf(relu_(S.w ),a4.w,d4.w);
        N1.x=fmaf(relu_(N1.x),a4.x,d4.x); N1.y=fmaf(relu_(N1.y),a4.y,d4.y);
        N1.z=fmaf(relu_(N1.z),a4.z,d4.z); N1.w=fmaf(relu_(N1.w),a4.w,d4.w);
        N2.x=fmaf(relu_(N2.x),a4.x,d4.x); N2.y=fmaf(relu_(N2.y),a4.y,d4.y);
        N2.z=fmaf(relu_(N2.z),a4.z,d4.z); N2.w=fmaf(relu_(N2.w),a4.w,d4.w);
        N3.x=fmaf(relu_(N3.x),a4.x,d4.x); N3.y=fmaf(relu_(N3.y),a4.y,d4.y);
        N3.z=fmaf(relu_(N3.z),a4.z,d4.z); N3.w=fmaf(relu_(N3.w),a4.w,d4.w);
      }
      short8 lo,hi;
      #define FEAT(dst,i0,sv,av,bv,cv) \
        dst[i0+0]=(short)f2bf(sv); \
        dst[i0+1]=(short)f2bf(av+bv+cv); \
        dst[i0+2]=(short)f2bf(fabsf(av-bv)+fabsf(bv-cv)+fabsf(cv-av)); \
        dst[i0+3]=(short)f2bf(fmaxf(fmaxf(av,bv),cv));
      FEAT(lo,0,S.x,N1.x,N2.x,N3.x)
      FEAT(lo,4,S.y,N1.y,N2.y,N3.y)
      FEAT(hi,0,S.z,N1.z,N2.z,N3.z)
      FEAT(hi,4,S.w,N1.w,N2.w,N3.w)
      #undef FEAT
      u16* rowp=&Gs[pb][(size_t)gr*64];
      *(short8*)&rowp[(size_t)(((2*c4q  )^(gr&7))*8)]=lo;
      *(short8*)&rowp[(size_t)(((2*c4q+1)^(gr&7))*8)]=hi;
    }
  };

  f32x4 acc[NRF][4];
  #pragma unroll
  for (int rr=0;rr<NRF;rr++)
    #pragma unroll
    for (int cg=0;cg<4;cg++){ f32x4 z={0.f,0.f,0.f,0.f}; acc[rr][cg]=z; }

  short8 B0[4],B1[4];
  #pragma unroll
  for (int cg=0;cg<4;cg++) B0[cg]=BLD(cg,0);
  #pragma unroll
  for (int cg=0;cg<4;cg++) B1[cg]=BLD(cg,1);

  auto MSTEP=[&](int pb,int s){
    short8 A[NRF];
    #pragma unroll
    for (int rr=0;rr<NRF;rr++) A[rr]=ADS(pb,rr,0);
    #pragma unroll
    for (int rr=0;rr<NRF;rr++)
      #pragma unroll
      for (int cg=0;cg<4;cg++) acc[rr][cg]=mfma_bf16(A[rr],B0[cg],acc[rr][cg]);
    if (s+1<NSTEP){
      #pragma unroll
      for (int cg=0;cg<4;cg++) B0[cg]=BLD(cg,2*(s+1));   // prefetch next slice
    }
    #pragma unroll
    for (int rr=0;rr<NRF;rr++) A[rr]=ADS(pb,rr,1);
    #pragma unroll
    for (int rr=0;rr<NRF;rr++)
      #pragma unroll
      for (int cg=0;cg<4;cg++) acc[rr][cg]=mfma_bf16(A[rr],B1[cg],acc[rr][cg]);
    if (s+1<NSTEP){
      #pragma unroll
      for (int cg=0;cg<4;cg++) B1[cg]=BLD(cg,2*(s+1)+1);
    }
  };

  // ---- prologue: step 0 staged, step 1 gathers in flight ----
  float4 gA[ITEMS][4], gB[ITEMS][4];
  GLD(0,gA); BLDW(0,0,gA);
  GLD(1,gA);
  __syncthreads();

  // 2-deep pipeline: gathers for step s+2 issued at top of step s.
  for (int s=0;s<NSTEP;s+=2){
    if (s+2<NSTEP) GLD(s+2,gB);
    MSTEP(0,s);
    if (s+1<NSTEP) BLDW(1,s+1,gA);
    __syncthreads();
    if (s+3<NSTEP) GLD(s+3,gA);
    if (s+1<NSTEP) MSTEP(1,s+1);
    if (s+2<NSTEP) BLDW(0,s+2,gB);
    __syncthreads();
  }

  // ---- epilogue: (optional fused residual+relu) store + relu stats ----
  #pragma unroll
  for (int cg=0;cg<4;cg++){
    const int col=wc*64+cg*16+l15;
    float rs=0.f,rq=0.f;
    #pragma unroll
    for (int rr=0;rr<NRF;rr++){
      const size_t rbase=(size_t)blockIdx.x*BR + wm*WR + rr*16 + kq*4;
      #pragma unroll
      for (int q=0;q<4;q++){
        size_t idx=(rbase+q)*COUT+col;
        float v=acc[rr][cg][q];
        if (RES){ v += res[idx]; v = relu_(v); }
        out[idx]=v;
        if (STATS){ float rv = RES ? v : relu_(v); rs+=rv; rq+=rv*rv; }
      }
    }
    if (STATS){ atomicAdd(&ls[col],rs); atomicAdd(&lq[col],rq); }
  }
  if (STATS){
    __syncthreads();
    const int part=blockIdx.x&(NPART-1);
    for (int i=t;i<COUT;i+=T){
      atomicAdd(&psum[(size_t)part*256+i],ls[i]);
      atomicAdd(&psum[(size_t)(NPART+part)*256+i],lq[i]);
    }
  }
}

// ---------------------------------------------------------------------------
// fp32 conv path (tiny 9->64 conv only)
// ---------------------------------------------------------------------------
template<int CIN,int COUT,bool BN,bool STATS>
__global__ __launch_bounds__(256) void conv_kernel(
    const float* __restrict__ xin, const int* __restrict__ nbr,
    const float* __restrict__ Wt, const float* __restrict__ bn_a,
    const float* __restrict__ bn_d,
    float* __restrict__ out, float* __restrict__ psum, int F)
{
  constexpr int K = 4*CIN;
  constexpr int ROWLEN = K + 4;
  __shared__ float Gs[TILE_F][ROWLEN];
  __shared__ int   nI[TILE_F*3];
  __shared__ float ls[STATS?COUT:1];
  __shared__ float lq[STATS?COUT:1];
  const int t = threadIdx.x;
  const int fbase = blockIdx.x*TILE_F;
  const int b = blockIdx.y;
  const float* __restrict__ xb = xin + (size_t)b*F*CIN;

  if (t < TILE_F*3){ int fi=t/3, j=t-fi*3; int fg=fbase+fi; nI[t]=(fg<F)?nbr[fg*3+j]:0; }
  if (STATS){ for (int i=t;i<COUT;i+=256){ ls[i]=0.f; lq[i]=0.f; } }
  __syncthreads();

  for (int idx=t; idx<TILE_F*CIN; idx+=256){
    int fi=idx/CIN, c=idx-fi*CIN;
    int fg=fbase+fi;
    float* dst=&Gs[fi][4*c];
    if (fg<F){
      int i1=nI[fi*3], i2=nI[fi*3+1], i3=nI[fi*3+2];
      float s =xb[(size_t)fg*CIN+c];
      float v1=xb[(size_t)i1*CIN+c];
      float v2=xb[(size_t)i2*CIN+c];
      float v3=xb[(size_t)i3*CIN+c];
      if (BN){ float a=bn_a[c], dd=bn_d[c];
        s=fmaf(relu_(s),a,dd); v1=fmaf(relu_(v1),a,dd);
        v2=fmaf(relu_(v2),a,dd); v3=fmaf(relu_(v3),a,dd); }
      dst[0]=s; dst[1]=v1+v2+v3;
      dst[2]=fabsf(v1-v2)+fabsf(v2-v3)+fabsf(v3-v1);
      dst[3]=fmaxf(fmaxf(v1,v2),v3);
    } else { dst[0]=0.f;dst[1]=0.f;dst[2]=0.f;dst[3]=0.f; }
  }
  __syncthreads();

  constexpr int OQ=COUT/4;
  constexpr int R=256/OQ;
  constexpr int FPT=TILE_F/R;
  const int col=t%OQ, row=t/OQ;
  const int o0=col*4, f0=row*FPT;
  float4 acc[FPT];
  #pragma unroll
  for (int fi=0;fi<FPT;fi++){ acc[fi].x=0.f;acc[fi].y=0.f;acc[fi].z=0.f;acc[fi].w=0.f; }

  for (int k=0;k<K;k+=4){
    float4 w0=*(const float4*)&Wt[(size_t)(k+0)*COUT+o0];
    float4 w1=*(const float4*)&Wt[(size_t)(k+1)*COUT+o0];
    float4 w2=*(const float4*)&Wt[(size_t)(k+2)*COUT+o0];
    float4 w3=*(const float4*)&Wt[(size_t)(k+3)*COUT+o0];
    #pragma unroll
    for (int fi=0;fi<FPT;fi++){
      float4 g=*(const float4*)&Gs[f0+fi][k];
      acc[fi].x=fmaf(g.x,w0.x,fmaf(g.y,w1.x,fmaf(g.z,w2.x,fmaf(g.w,w3.x,acc[fi].x))));
      acc[fi].y=fmaf(g.x,w0.y,fmaf(g.y,w1.y,fmaf(g.z,w2.y,fmaf(g.w,w3.y,acc[fi].y))));
      acc[fi].z=fmaf(g.x,w0.z,fmaf(g.y,w1.z,fmaf(g.z,w2.z,fmaf(g.w,w3.z,acc[fi].z))));
      acc[fi].w=fmaf(g.x,w0.w,fmaf(g.y,w1.w,fmaf(g.z,w2.w,fmaf(g.w,w3.w,acc[fi].w))));
    }
  }

  float4 rs={0,0,0,0}, rq={0,0,0,0};
  #pragma unroll
  for (int fi=0;fi<FPT;fi++){
    int fg=fbase+f0+fi;
    if (fg<F){
      *(float4*)&out[((size_t)b*F+fg)*COUT+o0]=acc[fi];
      if (STATS){
        float rx=relu_(acc[fi].x), ry=relu_(acc[fi].y);
        float rz=relu_(acc[fi].z), rw=relu_(acc[fi].w);
        rs.x+=rx; rs.y+=ry; rs.z+=rz; rs.w+=rw;
        rq.x+=rx*rx; rq.y+=ry*ry; rq.z+=rz*rz; rq.w+=rw*rw;
      }
    }
  }
  if (STATS){
    atomicAdd(&ls[o0+0],rs.x); atomicAdd(&ls[o0+1],rs.y);
    atomicAdd(&ls[o0+2],rs.z); atomicAdd(&ls[o0+3],rs.w);
    atomicAdd(&lq[o0+0],rq.x); atomicAdd(&lq[o0+1],rq.y);
    atomicAdd(&lq[o0+2],rq.z); atomicAdd(&lq[o0+3],rq.w);
    __syncthreads();
    int part=(blockIdx.y*gridDim.x+blockIdx.x)&(NPART-1);
    for (int i=t;i<COUT;i+=256){
      atomicAdd(&psum[(size_t)part*256+i], ls[i]);
      atomicAdd(&psum[(size_t)(NPART+part)*256+i], lq[i]);
    }
  }
}

// pool with folded BN finalize: aS/dS computed from psum partials per block
__global__ __launch_bounds__(256) void pool_kernel(
    const float* __restrict__ z, const int* __restrict__ pl,
    const float* __restrict__ ps_in, const float* __restrict__ gamma,
    const float* __restrict__ beta,
    float* __restrict__ out, int C4, int F, int Fn, int n4, float invN)
{
  __shared__ float aS[256], dS[256];
  const int C=C4*4;
  const int t=threadIdx.x;
  if (t<C){
    float s=0.f,q=0.f;
    #pragma unroll 4
    for (int p=0;p<NPART;p++){ s+=ps_in[p*256+t]; q+=ps_in[(NPART+p)*256+t]; }
    float m=s*invN, v=q*invN-m*m;
    float ai=gamma[t]*rsqrtf(v+1e-5f);
    aS[t]=ai; dS[t]=beta[t]-m*ai;
  }
  __syncthreads();
  for (int i=blockIdx.x*256+t; i<n4; i+=gridDim.x*256){
    int c4=i%C4; int rest=i/C4; int p=rest%Fn; int b=rest/Fn;
    int p0=pl[p*3], p1=pl[p*3+1], p2=pl[p*3+2];
    float4 a4=*(const float4*)&aS[4*c4], d4=*(const float4*)&dS[4*c4];
    float4 v0=*(const float4*)&z[((size_t)b*F+p0)*C+4*c4];
    float4 v1=*(const float4*)&z[((size_t)b*F+p1)*C+4*c4];
    float4 v2=*(const float4*)&z[((size_t)b*F+p2)*C+4*c4];
    float4 r;
    r.x=(relu_(fmaf(v0.x,a4.x,d4.x))+relu_(fmaf(v1.x,a4.x,d4.x))+relu_(fmaf(v2.x,a4.x,d4.x)))*(1.f/3.f);
    r.y=(relu_(fmaf(v0.y,a4.y,d4.y))+relu_(fmaf(v1.y,a4.y,d4.y))+relu_(fmaf(v2.y,a4.y,d4.y)))*(1.f/3.f);
    r.z=(relu_(fmaf(v0.z,a4.z,d4.z))+relu_(fmaf(v1.z,a4.z,d4.z))+relu_(fmaf(v2.z,a4.z,d4.z)))*(1.f/3.f);
    r.w=(relu_(fmaf(v0.w,a4.w,d4.w))+relu_(fmaf(v1.w,a4.w,d4.w))+relu_(fmaf(v2.w,a4.w,d4.w)))*(1.f/3.f);
    *(float4*)&out[((size_t)b*Fn+p)*C+4*c4]=r;
  }
}

__global__ __launch_bounds__(256) void colsum_kernel(
    const float* __restrict__ x, float* __restrict__ bc, int F, int chunk)
{
  int b=blockIdx.y; int f0=blockIdx.x*chunk;
  int c=threadIdx.x;
  int fe=f0+chunk; if (fe>F) fe=F;
  float s=0.f;
  for (int f=f0;f<fe;f++) s+=x[((size_t)b*F+f)*256+c];
  atomicAdd(&bc[b*256+c], s);
}

__global__ __launch_bounds__(256) void head_kernel(
    const float* __restrict__ bc, const float* __restrict__ w1,
    const float* __restrict__ b1, const float* __restrict__ w2,
    const float* __restrict__ b2, float* __restrict__ outp, float invF)
{
  __shared__ float xm[8*256];
  __shared__ float h[8*128];
  int t=threadIdx.x;
  for (int i=t;i<2048;i+=256) xm[i]=bc[i]*invF;
  __syncthreads();
  #pragma unroll
  for (int r=0;r<4;r++){
    int idx=t+r*256; int b=idx>>7, j=idx&127;
    float s=b1[j];
    for (int c=0;c<256;c++) s=fmaf(xm[b*256+c],w1[j*256+c],s);
    h[idx]=relu_(s);
  }
  __syncthreads();
  if (t<8){
    float s=b2[0];
    for (int j=0;j<128;j++) s=fmaf(h[t*128+j],w2[j],s);
    outp[t]=1.f/(1.f+expf(-s));
  }
}

__global__ __launch_bounds__(256) void transpose_in_kernel(
    const float* __restrict__ x, float* __restrict__ xt, int F)
{
  int i=blockIdx.x*256+threadIdx.x;
  int total=8*9*F;
  if (i<total){ int f=i%F; int c=(i/F)%9; int b=i/(9*F);
    xt[((size_t)b*F+f)*9+c]=x[i]; }
}

__global__ __launch_bounds__(256) void transpose_w_kernel(
    const float* __restrict__ w, float* __restrict__ wt, int K, int COUT)
{
  int i=blockIdx.x*256+threadIdx.x;
  if (i<K*COUT){ int o=i/K, k=i-o*K; wt[(size_t)k*COUT+o]=w[i]; }
}

__global__ __launch_bounds__(256) void cvt_bf16_kernel(
    const float* __restrict__ w, u16* __restrict__ o, int n)
{
  int i=blockIdx.x*256+threadIdx.x;
  if (i<n) o[i]=f2bf(w[i]);
}

// ---------------------------------------------------------------------------

template<int CIN,int COUT,int WR,int NWR,bool BN,bool STATS,bool RES>
static void launch_mconv(const float* xin, const int* nbr, const u16* wbf,
                         const float* ps_in, const float* gamma, const float* beta,
                         const float* res, float* out, float* ps_out,
                         int F, float invN, hipStream_t stream)
{
  constexpr int T  = NWR*(COUT/64)*64;
  constexpr int BR = NWR*WR;
  int M = 8*F;
  mconv_kernel<CIN,COUT,WR,NWR,BN,STATS,RES><<<M/BR, T, 0, stream>>>(
      xin,nbr,wbf,ps_in,gamma,beta,res,out,ps_out,F,invN);
}

extern "C" void kernel_launch(void* const* d_in, const int* in_sizes, int n_in,
                              void* d_out, int out_size, void* d_ws, size_t ws_size,
                              hipStream_t stream)
{
  const float* x    =(const float*)d_in[0];
  const int*  nbr0  =(const int*)d_in[1];
  const int*  pool0 =(const int*)d_in[2];
  const int*  nbr1  =(const int*)d_in[3];
  const int*  pool1 =(const int*)d_in[4];
  const int*  nbr2  =(const int*)d_in[5];
  const int*  pool2 =(const int*)d_in[6];
  const float* wc0  =(const float*)d_in[7];
  const float* ws0  =(const float*)d_in[8];
  const float* bng0 =(const float*)d_in[9];
  const float* bnb0 =(const float*)d_in[10];
  const float* ng0  =(const float*)d_in[11];
  const float* nb0  =(const float*)d_in[12];
  const float* wc1  =(const float*)d_in[13];
  const float* ws1  =(const float*)d_in[14];
  const float* bng1 =(const float*)d_in[15];
  const float* bnb1 =(const float*)d_in[16];
  const float* ng1  =(const float*)d_in[17];
  const float* nb1  =(const float*)d_in[18];
  const float* wc2  =(const float*)d_in[19];
  const float* ws2  =(const float*)d_in[20];
  const float* bng2 =(const float*)d_in[21];
  const float* bnb2 =(const float*)d_in[22];
  const float* ng2  =(const float*)d_in[23];
  const float* nb2  =(const float*)d_in[24];
  const float* fc1w =(const float*)d_in[25];
  const float* fc1b =(const float*)d_in[26];
  const float* fc2w =(const float*)d_in[27];
  const float* fc2b =(const float*)d_in[28];
  float* outp=(float*)d_out;

  char* base=(char*)d_ws;
  size_t off=0;
  auto alloc=[&](size_t nbytes)->void*{
    void* p=base+off; off=(off+nbytes+255)&~(size_t)255; return p; };

  float* psum0 =(float*)alloc((size_t)12*131072);
  float* bc    =(float*)alloc(8192);
  float* wt_wc0=(float*)alloc((size_t)36*64*4);
  u16*   bws0  =(u16*)alloc((size_t)3*16384*2);
  u16*   bwc1  =(u16*)alloc((size_t)32768*2);
  u16*   bws1  =(u16*)alloc((size_t)3*65536*2);
  u16*   bwc2  =(u16*)alloc((size_t)131072*2);
  u16*   bws2  =(u16*)alloc((size_t)3*262144*2);
  float* xT    =(float*)alloc((size_t)8*12000*9*4);
  float* B0    =(float*)alloc((size_t)49152000);
  float* B1    =(float*)alloc((size_t)49152000);
  float* B2    =(float*)alloc((size_t)49152000);
  if (off>ws_size) return;

  auto PS=[&](int i){ return psum0+(size_t)i*32768; };

  hipMemsetAsync(psum0,0,(size_t)12*131072+8192,stream);

  { int n=8*9*12000; transpose_in_kernel<<<(n+255)/256,256,0,stream>>>(x,xT,12000); }
  { int n=36*64; transpose_w_kernel<<<(n+255)/256,256,0,stream>>>(wc0,wt_wc0,36,64); }
  auto cv=[&](const float* w,u16* o,int n){
    cvt_bf16_kernel<<<(n+255)/256,256,0,stream>>>(w,o,n); };
  cv(ws0,bws0,3*16384);
  cv(wc1,bwc1,32768);
  cv(ws1,bws1,3*65536);
  cv(wc2,bwc2,131072);
  cv(ws2,bws2,3*262144);

  // -------- stage 0: F=12000, 9 -> 64 --------
  {
    const int F=12000; const float invN=1.f/(8.f*F);
    dim3 grid((F+TILE_F-1)/TILE_F, 8);
    conv_kernel<9,64,false,true><<<grid,256,0,stream>>>(xT,nbr0,wt_wc0,nullptr,nullptr,B0,PS(0),F);
    launch_mconv<64,64,32,2,true,true ,false>(B0,nbr0,bws0,        PS(0),bng0,     bnb0,     nullptr,B1,PS(1),F,invN,stream);
    launch_mconv<64,64,32,2,true,true ,false>(B1,nbr0,bws0+16384,  PS(1),bng0+64,  bnb0+64,  nullptr,B2,PS(2),F,invN,stream);
    // 4th conv: fused residual relu(y + B0) + stats for the outer BN (PS(3))
    launch_mconv<64,64,32,2,true,true ,true >(B2,nbr0,bws0+32768,  PS(2),bng0+128, bnb0+128, B0,     B1,PS(3),F,invN,stream);
    int n4p=8*9000*16; int gp=(n4p+255)/256; if (gp>2048) gp=2048;
    pool_kernel<<<gp,256,0,stream>>>(B1,pool0,PS(3),ng0,nb0,B2,16,F,9000,n4p,invN);
  }
  // -------- stage 1: F=9000, 64 -> 128 --------
  {
    const int F=9000; const float invN=1.f/(8.f*F);
    launch_mconv<64,128,64,1,false,true ,false>(B2,nbr1,bwc1,         nullptr,nullptr,  nullptr,  nullptr,B0,PS(4),F,invN,stream);
    launch_mconv<128,128,64,1,true,true ,false>(B0,nbr1,bws1,         PS(4),bng1,      bnb1,     nullptr,B1,PS(5),F,invN,stream);
    launch_mconv<128,128,64,1,true,true ,false>(B1,nbr1,bws1+65536,   PS(5),bng1+128,  bnb1+128, nullptr,B2,PS(6),F,invN,stream);
    launch_mconv<128,128,64,1,true,true ,true >(B2,nbr1,bws1+131072,  PS(6),bng1+256,  bnb1+256, B0,     B1,PS(7),F,invN,stream);
    int n4p=8*6000*32; int gp=(n4p+255)/256; if (gp>2048) gp=2048;
    pool_kernel<<<gp,256,0,stream>>>(B1,pool1,PS(7),ng1,nb1,B0,32,F,6000,n4p,invN);
  }
  // -------- stage 2: F=6000, 128 -> 256 --------
  {
    const int F=6000; const float invN=1.f/(8.f*F);
    launch_mconv<128,256,64,1,false,true ,false>(B0,nbr2,bwc2,         nullptr,nullptr,  nullptr,  nullptr,B1,PS(8),F,invN,stream);
    launch_mconv<256,256,64,1,true,true ,false>(B1,nbr2,bws2,         PS(8), bng2,     bnb2,     nullptr,B2,PS(9),F,invN,stream);
    launch_mconv<256,256,64,1,true,true ,false>(B2,nbr2,bws2+262144,  PS(9), bng2+256, bnb2+256, nullptr,B0,PS(10),F,invN,stream);
    launch_mconv<256,256,64,1,true,true ,true >(B0,nbr2,bws2+524288,  PS(10),bng2+512, bnb2+512, B1,     B2,PS(11),F,invN,stream);
    int n4p=8*4000*64; int gp=(n4p+255)/256; if (gp>2048) gp=2048;
    pool_kernel<<<gp,256,0,stream>>>(B2,pool2,PS(11),ng2,nb2,B0,64,F,4000,n4p,invN);
    colsum_kernel<<<dim3(16,8),256,0,stream>>>(B0,bc,4000,250);
  }
  head_kernel<<<1,256,0,stream>>>(bc,fc1w,fc1b,fc2w,fc2b,outp,1.f/4000.f);
}

// Round 10
// 918.406 us; speedup vs baseline: 3.9072x; 1.0517x over previous
//
#include <hip/hip_runtime.h>
#include <math.h>

#define NPART 64
#define TILE_F 16

typedef unsigned short u16;
typedef __attribute__((ext_vector_type(8))) short short8;
typedef __attribute__((ext_vector_type(4))) float f32x4;

__device__ __forceinline__ float relu_(float v){ return fmaxf(v, 0.f); }

__device__ __forceinline__ u16 f2bf(float x){
  unsigned u = __float_as_uint(x);
  u = (u + 0x7fffu + ((u >> 16) & 1u)) >> 16;
  return (u16)u;
}

static __device__ __forceinline__ f32x4 mfma_bf16(short8 a, short8 b, f32x4 c){
  asm("v_mfma_f32_16x16x32_bf16 %0, %1, %2, %0" : "+v"(c) : "v"(a), "v"(b));
  return c;
}

// ---------------------------------------------------------------------------
// MFMA mesh-conv (round-7 verified loop), KSTEP=64, B-slice prefetch,
// BN finalize folded into prologue, optional fused residual epilogue.
// Batch-per-XCD grid: grid = 8 * ceil(F/BR); batch = blockIdx.x & 7 so the
// round-robin workgroup->XCD mapping pins each batch's slice to one L2.
//   out[r,o] = sum_k G[r,k] * W[o,k];  r = b*F+f, k = 4c+j
// ---------------------------------------------------------------------------
template<int CIN,int COUT,int WR,int NWR,bool BN,bool STATS,bool RES>
__global__ __launch_bounds__(NWR*(COUT/64)*64) void mconv_kernel(
    const float* __restrict__ xin, const int* __restrict__ nbr,
    const u16* __restrict__ wbf,
    const float* __restrict__ ps_in, const float* __restrict__ gamma,
    const float* __restrict__ beta, const float* __restrict__ res,
    float* __restrict__ out, float* __restrict__ psum,
    int F, float invN)
{
  constexpr int nWc = COUT/64;
  constexpr int T   = NWR*nWc*64;
  constexpr int BR  = NWR*WR;
  constexpr int K   = 4*CIN;
  constexpr int NSTEP = CIN/16;       // 16 channels (64 k) per step
  constexpr int ITEMS = (BR*4)/T;     // gather work items per thread
  constexpr int NRF   = WR/16;        // row fragments per wave

  __shared__ __align__(16) u16 Gs[2][BR*64];
  __shared__ float ls[STATS?COUT:1], lq[STATS?COUT:1];
  __shared__ float aS[BN?CIN:1], dS[BN?CIN:1];

  const int t=threadIdx.x, lane=t&63, wid=t>>6;
  const int wm=wid/nWc, wc=wid%nWc;
  const int l15=lane&15, kq=lane>>4;

  const int batch = blockIdx.x & 7;       // XCD-locality: one batch per XCD
  const int row0  = (blockIdx.x >> 3) * BR;

  if (BN){
    for (int c=t;c<CIN;c+=T){
      float s=0.f,q=0.f;
      #pragma unroll 4
      for (int p=0;p<NPART;p++){ s+=ps_in[p*256+c]; q+=ps_in[(NPART+p)*256+c]; }
      float m=s*invN, v=q*invN-m*m;
      float ai=gamma[c]*rsqrtf(v+1e-5f);
      aS[c]=ai; dS[c]=beta[c]-m*ai;
    }
  }
  if (STATS){ for (int i=t;i<COUT;i+=T){ ls[i]=0.f; lq[i]=0.f; } }
  __syncthreads();

  // ---- gather pointers (fixed rows/channel-quads per thread) ----
  const float *P0[ITEMS],*P1[ITEMS],*P2[ITEMS],*P3[ITEMS];
  #pragma unroll
  for (int i=0;i<ITEMS;i++){
    int idx=i*T+t, gr=idx>>2, c4q=idx&3;
    int f=row0+gr;
    if (f>=F) f=F-1;                      // clamp tail rows (outputs discarded)
    int i1=nbr[f*3+0], i2=nbr[f*3+1], i3=nbr[f*3+2];
    const float* xb=xin+(size_t)batch*F*CIN+c4q*4;
    P0[i]=xb+(size_t)f *CIN; P1[i]=xb+(size_t)i1*CIN;
    P2[i]=xb+(size_t)i2*CIN; P3[i]=xb+(size_t)i3*CIN;
  }

  const u16* wp = wbf + (size_t)(wc*64+l15)*K + kq*8;
  auto BLD=[&](int cg,int j)->short8{
    return *(const short8*)(wp + (size_t)cg*16*K + (size_t)j*32);
  };
  auto ADS=[&](int pb,int rr,int h)->short8{
    int r=wm*WR+rr*16+l15;
    int sl=h*4+kq;
    return *(const short8*)&Gs[pb][(size_t)r*64 + (size_t)((sl^(r&7))*8)];
  };
  auto GLD=[&](int s,float4 (&g)[ITEMS][4]){
    #pragma unroll
    for (int i=0;i<ITEMS;i++){
      g[i][0]=*(const float4*)(P0[i]+s*16);
      g[i][1]=*(const float4*)(P1[i]+s*16);
      g[i][2]=*(const float4*)(P2[i]+s*16);
      g[i][3]=*(const float4*)(P3[i]+s*16);
    }
  };
  auto BLDW=[&](int pb,int s,float4 (&g)[ITEMS][4]){
    #pragma unroll
    for (int i=0;i<ITEMS;i++){
      int idx=i*T+t, gr=idx>>2, c4q=idx&3;
      float4 S=g[i][0],N1=g[i][1],N2=g[i][2],N3=g[i][3];
      if (BN){
        float4 a4=*(const float4*)&aS[s*16+c4q*4];
        float4 d4=*(const float4*)&dS[s*16+c4q*4];
        S.x =fmaf(relu_(S.x ),a4.x,d4.x); S.y =fmaf(relu_(S.y ),a4.y,d4.y);
        S.z =fmaf(relu_(S.z ),a4.z,d4.z); S.w =fmaf(relu_(S.w ),a4.w,d4.w);
        N1.x=fmaf(relu_(N1.x),a4.x,d4.x); N1.y=fmaf(relu_(N1.y),a4.y,d4.y);
        N1.z=fmaf(relu_(N1.z),a4.z,d4.z); N1.w=fmaf(relu_(N1.w),a4.w,d4.w);
        N2.x=fmaf(relu_(N2.x),a4.x,d4.x); N2.y=fmaf(relu_(N2.y),a4.y,d4.y);
        N2.z=fmaf(relu_(N2.z),a4.z,d4.z); N2.w=fmaf(relu_(N2.w),a4.w,d4.w);
        N3.x=fmaf(relu_(N3.x),a4.x,d4.x); N3.y=fmaf(relu_(N3.y),a4.y,d4.y);
        N3.z=fmaf(relu_(N3.z),a4.z,d4.z); N3.w=fmaf(relu_(N3.w),a4.w,d4.w);
      }
      short8 lo,hi;
      #define FEAT(dst,i0,sv,av,bv,cv) \
        dst[i0+0]=(short)f2bf(sv); \
        dst[i0+1]=(short)f2bf(av+bv+cv); \
        dst[i0+2]=(short)f2bf(fabsf(av-bv)+fabsf(bv-cv)+fabsf(cv-av)); \
        dst[i0+3]=(short)f2bf(fmaxf(fmaxf(av,bv),cv));
      FEAT(lo,0,S.x,N1.x,N2.x,N3.x)
      FEAT(lo,4,S.y,N1.y,N2.y,N3.y)
      FEAT(hi,0,S.z,N1.z,N2.z,N3.z)
      FEAT(hi,4,S.w,N1.w,N2.w,N3.w)
      #undef FEAT
      u16* rowp=&Gs[pb][(size_t)gr*64];
      *(short8*)&rowp[(size_t)(((2*c4q  )^(gr&7))*8)]=lo;
      *(short8*)&rowp[(size_t)(((2*c4q+1)^(gr&7))*8)]=hi;
    }
  };

  f32x4 acc[NRF][4];
  #pragma unroll
  for (int rr=0;rr<NRF;rr++)
    #pragma unroll
    for (int cg=0;cg<4;cg++){ f32x4 z={0.f,0.f,0.f,0.f}; acc[rr][cg]=z; }

  short8 B0[4],B1[4];
  #pragma unroll
  for (int cg=0;cg<4;cg++) B0[cg]=BLD(cg,0);
  #pragma unroll
  for (int cg=0;cg<4;cg++) B1[cg]=BLD(cg,1);

  { float4 g0[ITEMS][4]; GLD(0,g0); BLDW(0,0,g0); }
  __syncthreads();

  // round-7 verified single-step pipeline (79 us measured; 2-deep regressed)
  #pragma unroll 2
  for (int s=0;s<NSTEP;s++){
    const int pb=s&1;
    float4 g[ITEMS][4];
    if (s+1<NSTEP) GLD(s+1,g);               // issue gathers for next step
    short8 A[NRF];
    #pragma unroll
    for (int rr=0;rr<NRF;rr++) A[rr]=ADS(pb,rr,0);
    #pragma unroll
    for (int rr=0;rr<NRF;rr++)
      #pragma unroll
      for (int cg=0;cg<4;cg++) acc[rr][cg]=mfma_bf16(A[rr],B0[cg],acc[rr][cg]);
    if (s+1<NSTEP){
      #pragma unroll
      for (int cg=0;cg<4;cg++) B0[cg]=BLD(cg,2*(s+1));   // prefetch next slice
    }
    #pragma unroll
    for (int rr=0;rr<NRF;rr++) A[rr]=ADS(pb,rr,1);
    #pragma unroll
    for (int rr=0;rr<NRF;rr++)
      #pragma unroll
      for (int cg=0;cg<4;cg++) acc[rr][cg]=mfma_bf16(A[rr],B1[cg],acc[rr][cg]);
    if (s+1<NSTEP){
      #pragma unroll
      for (int cg=0;cg<4;cg++) B1[cg]=BLD(cg,2*(s+1)+1);
      BLDW(pb^1,s+1,g);                      // features -> other buffer
    }
    __syncthreads();
  }

  // ---- epilogue: (optional fused residual+relu) store + relu stats ----
  const size_t bbase=(size_t)batch*F;
  #pragma unroll
  for (int cg=0;cg<4;cg++){
    const int col=wc*64+cg*16+l15;
    float rs=0.f,rq=0.f;
    #pragma unroll
    for (int rr=0;rr<NRF;rr++){
      const int r0=row0 + wm*WR + rr*16 + kq*4;
      #pragma unroll
      for (int q=0;q<4;q++){
        int r=r0+q;
        if (r<F){
          size_t idx=(bbase+r)*COUT+col;
          float v=acc[rr][cg][q];
          if (RES){ v += res[idx]; v = relu_(v); }
          out[idx]=v;
          if (STATS){ float rv = RES ? v : relu_(v); rs+=rv; rq+=rv*rv; }
        }
      }
    }
    if (STATS){ atomicAdd(&ls[col],rs); atomicAdd(&lq[col],rq); }
  }
  if (STATS){
    __syncthreads();
    const int part=blockIdx.x&(NPART-1);
    for (int i=t;i<COUT;i+=T){
      atomicAdd(&psum[(size_t)part*256+i],ls[i]);
      atomicAdd(&psum[(size_t)(NPART+part)*256+i],lq[i]);
    }
  }
}

// ---------------------------------------------------------------------------
// fp32 conv path (tiny 9->64 conv only)
// ---------------------------------------------------------------------------
template<int CIN,int COUT,bool BN,bool STATS>
__global__ __launch_bounds__(256) void conv_kernel(
    const float* __restrict__ xin, const int* __restrict__ nbr,
    const float* __restrict__ Wt, const float* __restrict__ bn_a,
    const float* __restrict__ bn_d,
    float* __restrict__ out, float* __restrict__ psum, int F)
{
  constexpr int K = 4*CIN;
  constexpr int ROWLEN = K + 4;
  __shared__ float Gs[TILE_F][ROWLEN];
  __shared__ int   nI[TILE_F*3];
  __shared__ float ls[STATS?COUT:1];
  __shared__ float lq[STATS?COUT:1];
  const int t = threadIdx.x;
  const int fbase = blockIdx.x*TILE_F;
  const int b = blockIdx.y;
  const float* __restrict__ xb = xin + (size_t)b*F*CIN;

  if (t < TILE_F*3){ int fi=t/3, j=t-fi*3; int fg=fbase+fi; nI[t]=(fg<F)?nbr[fg*3+j]:0; }
  if (STATS){ for (int i=t;i<COUT;i+=256){ ls[i]=0.f; lq[i]=0.f; } }
  __syncthreads();

  for (int idx=t; idx<TILE_F*CIN; idx+=256){
    int fi=idx/CIN, c=idx-fi*CIN;
    int fg=fbase+fi;
    float* dst=&Gs[fi][4*c];
    if (fg<F){
      int i1=nI[fi*3], i2=nI[fi*3+1], i3=nI[fi*3+2];
      float s =xb[(size_t)fg*CIN+c];
      float v1=xb[(size_t)i1*CIN+c];
      float v2=xb[(size_t)i2*CIN+c];
      float v3=xb[(size_t)i3*CIN+c];
      if (BN){ float a=bn_a[c], dd=bn_d[c];
        s=fmaf(relu_(s),a,dd); v1=fmaf(relu_(v1),a,dd);
        v2=fmaf(relu_(v2),a,dd); v3=fmaf(relu_(v3),a,dd); }
      dst[0]=s; dst[1]=v1+v2+v3;
      dst[2]=fabsf(v1-v2)+fabsf(v2-v3)+fabsf(v3-v1);
      dst[3]=fmaxf(fmaxf(v1,v2),v3);
    } else { dst[0]=0.f;dst[1]=0.f;dst[2]=0.f;dst[3]=0.f; }
  }
  __syncthreads();

  constexpr int OQ=COUT/4;
  constexpr int R=256/OQ;
  constexpr int FPT=TILE_F/R;
  const int col=t%OQ, row=t/OQ;
  const int o0=col*4, f0=row*FPT;
  float4 acc[FPT];
  #pragma unroll
  for (int fi=0;fi<FPT;fi++){ acc[fi].x=0.f;acc[fi].y=0.f;acc[fi].z=0.f;acc[fi].w=0.f; }

  for (int k=0;k<K;k+=4){
    float4 w0=*(const float4*)&Wt[(size_t)(k+0)*COUT+o0];
    float4 w1=*(const float4*)&Wt[(size_t)(k+1)*COUT+o0];
    float4 w2=*(const float4*)&Wt[(size_t)(k+2)*COUT+o0];
    float4 w3=*(const float4*)&Wt[(size_t)(k+3)*COUT+o0];
    #pragma unroll
    for (int fi=0;fi<FPT;fi++){
      float4 g=*(const float4*)&Gs[f0+fi][k];
      acc[fi].x=fmaf(g.x,w0.x,fmaf(g.y,w1.x,fmaf(g.z,w2.x,fmaf(g.w,w3.x,acc[fi].x))));
      acc[fi].y=fmaf(g.x,w0.y,fmaf(g.y,w1.y,fmaf(g.z,w2.y,fmaf(g.w,w3.y,acc[fi].y))));
      acc[fi].z=fmaf(g.x,w0.z,fmaf(g.y,w1.z,fmaf(g.z,w2.z,fmaf(g.w,w3.z,acc[fi].z))));
      acc[fi].w=fmaf(g.x,w0.w,fmaf(g.y,w1.w,fmaf(g.z,w2.w,fmaf(g.w,w3.w,acc[fi].w))));
    }
  }

  float4 rs={0,0,0,0}, rq={0,0,0,0};
  #pragma unroll
  for (int fi=0;fi<FPT;fi++){
    int fg=fbase+f0+fi;
    if (fg<F){
      *(float4*)&out[((size_t)b*F+fg)*COUT+o0]=acc[fi];
      if (STATS){
        float rx=relu_(acc[fi].x), ry=relu_(acc[fi].y);
        float rz=relu_(acc[fi].z), rw=relu_(acc[fi].w);
        rs.x+=rx; rs.y+=ry; rs.z+=rz; rs.w+=rw;
        rq.x+=rx*rx; rq.y+=ry*ry; rq.z+=rz*rz; rq.w+=rw*rw;
      }
    }
  }
  if (STATS){
    atomicAdd(&ls[o0+0],rs.x); atomicAdd(&ls[o0+1],rs.y);
    atomicAdd(&ls[o0+2],rs.z); atomicAdd(&ls[o0+3],rs.w);
    atomicAdd(&lq[o0+0],rq.x); atomicAdd(&lq[o0+1],rq.y);
    atomicAdd(&lq[o0+2],rq.z); atomicAdd(&lq[o0+3],rq.w);
    __syncthreads();
    int part=(blockIdx.y*gridDim.x+blockIdx.x)&(NPART-1);
    for (int i=t;i<COUT;i+=256){
      atomicAdd(&psum[(size_t)part*256+i], ls[i]);
      atomicAdd(&psum[(size_t)(NPART+part)*256+i], lq[i]);
    }
  }
}

// pool with folded BN finalize: aS/dS computed from psum partials per block
__global__ __launch_bounds__(256) void pool_kernel(
    const float* __restrict__ z, const int* __restrict__ pl,
    const float* __restrict__ ps_in, const float* __restrict__ gamma,
    const float* __restrict__ beta,
    float* __restrict__ out, int C4, int F, int Fn, int n4, float invN)
{
  __shared__ float aS[256], dS[256];
  const int C=C4*4;
  const int t=threadIdx.x;
  if (t<C){
    float s=0.f,q=0.f;
    #pragma unroll 4
    for (int p=0;p<NPART;p++){ s+=ps_in[p*256+t]; q+=ps_in[(NPART+p)*256+t]; }
    float m=s*invN, v=q*invN-m*m;
    float ai=gamma[t]*rsqrtf(v+1e-5f);
    aS[t]=ai; dS[t]=beta[t]-m*ai;
  }
  __syncthreads();
  for (int i=blockIdx.x*256+t; i<n4; i+=gridDim.x*256){
    int c4=i%C4; int rest=i/C4; int p=rest%Fn; int b=rest/Fn;
    int p0=pl[p*3], p1=pl[p*3+1], p2=pl[p*3+2];
    float4 a4=*(const float4*)&aS[4*c4], d4=*(const float4*)&dS[4*c4];
    float4 v0=*(const float4*)&z[((size_t)b*F+p0)*C+4*c4];
    float4 v1=*(const float4*)&z[((size_t)b*F+p1)*C+4*c4];
    float4 v2=*(const float4*)&z[((size_t)b*F+p2)*C+4*c4];
    float4 r;
    r.x=(relu_(fmaf(v0.x,a4.x,d4.x))+relu_(fmaf(v1.x,a4.x,d4.x))+relu_(fmaf(v2.x,a4.x,d4.x)))*(1.f/3.f);
    r.y=(relu_(fmaf(v0.y,a4.y,d4.y))+relu_(fmaf(v1.y,a4.y,d4.y))+relu_(fmaf(v2.y,a4.y,d4.y)))*(1.f/3.f);
    r.z=(relu_(fmaf(v0.z,a4.z,d4.z))+relu_(fmaf(v1.z,a4.z,d4.z))+relu_(fmaf(v2.z,a4.z,d4.z)))*(1.f/3.f);
    r.w=(relu_(fmaf(v0.w,a4.w,d4.w))+relu_(fmaf(v1.w,a4.w,d4.w))+relu_(fmaf(v2.w,a4.w,d4.w)))*(1.f/3.f);
    *(float4*)&out[((size_t)b*Fn+p)*C+4*c4]=r;
  }
}

__global__ __launch_bounds__(256) void colsum_kernel(
    const float* __restrict__ x, float* __restrict__ bc, int F, int chunk)
{
  int b=blockIdx.y; int f0=blockIdx.x*chunk;
  int c=threadIdx.x;
  int fe=f0+chunk; if (fe>F) fe=F;
  float s=0.f;
  for (int f=f0;f<fe;f++) s+=x[((size_t)b*F+f)*256+c];
  atomicAdd(&bc[b*256+c], s);
}

__global__ __launch_bounds__(256) void head_kernel(
    const float* __restrict__ bc, const float* __restrict__ w1,
    const float* __restrict__ b1, const float* __restrict__ w2,
    const float* __restrict__ b2, float* __restrict__ outp, float invF)
{
  __shared__ float xm[8*256];
  __shared__ float h[8*128];
  int t=threadIdx.x;
  for (int i=t;i<2048;i+=256) xm[i]=bc[i]*invF;
  __syncthreads();
  #pragma unroll
  for (int r=0;r<4;r++){
    int idx=t+r*256; int b=idx>>7, j=idx&127;
    float s=b1[j];
    for (int c=0;c<256;c++) s=fmaf(xm[b*256+c],w1[j*256+c],s);
    h[idx]=relu_(s);
  }
  __syncthreads();
  if (t<8){
    float s=b2[0];
    for (int j=0;j<128;j++) s=fmaf(h[t*128+j],w2[j],s);
    outp[t]=1.f/(1.f+expf(-s));
  }
}

__global__ __launch_bounds__(256) void transpose_in_kernel(
    const float* __restrict__ x, float* __restrict__ xt, int F)
{
  int i=blockIdx.x*256+threadIdx.x;
  int total=8*9*F;
  if (i<total){ int f=i%F; int c=(i/F)%9; int b=i/(9*F);
    xt[((size_t)b*F+f)*9+c]=x[i]; }
}

__global__ __launch_bounds__(256) void transpose_w_kernel(
    const float* __restrict__ w, float* __restrict__ wt, int K, int COUT)
{
  int i=blockIdx.x*256+threadIdx.x;
  if (i<K*COUT){ int o=i/K, k=i-o*K; wt[(size_t)k*COUT+o]=w[i]; }
}

__global__ __launch_bounds__(256) void cvt_bf16_kernel(
    const float* __restrict__ w, u16* __restrict__ o, int n)
{
  int i=blockIdx.x*256+threadIdx.x;
  if (i<n) o[i]=f2bf(w[i]);
}

// ---------------------------------------------------------------------------

template<int CIN,int COUT,int WR,int NWR,bool BN,bool STATS,bool RES>
static void launch_mconv(const float* xin, const int* nbr, const u16* wbf,
                         const float* ps_in, const float* gamma, const float* beta,
                         const float* res, float* out, float* ps_out,
                         int F, float invN, hipStream_t stream)
{
  constexpr int T  = NWR*(COUT/64)*64;
  constexpr int BR = NWR*WR;
  int nb = (F + BR - 1)/BR;
  mconv_kernel<CIN,COUT,WR,NWR,BN,STATS,RES><<<8*nb, T, 0, stream>>>(
      xin,nbr,wbf,ps_in,gamma,beta,res,out,ps_out,F,invN);
}

extern "C" void kernel_launch(void* const* d_in, const int* in_sizes, int n_in,
                              void* d_out, int out_size, void* d_ws, size_t ws_size,
                              hipStream_t stream)
{
  const float* x    =(const float*)d_in[0];
  const int*  nbr0  =(const int*)d_in[1];
  const int*  pool0 =(const int*)d_in[2];
  const int*  nbr1  =(const int*)d_in[3];
  const int*  pool1 =(const int*)d_in[4];
  const int*  nbr2  =(const int*)d_in[5];
  const int*  pool2 =(const int*)d_in[6];
  const float* wc0  =(const float*)d_in[7];
  const float* ws0  =(const float*)d_in[8];
  const float* bng0 =(const float*)d_in[9];
  const float* bnb0 =(const float*)d_in[10];
  const float* ng0  =(const float*)d_in[11];
  const float* nb0  =(const float*)d_in[12];
  const float* wc1  =(const float*)d_in[13];
  const float* ws1  =(const float*)d_in[14];
  const float* bng1 =(const float*)d_in[15];
  const float* bnb1 =(const float*)d_in[16];
  const float* ng1  =(const float*)d_in[17];
  const float* nb1  =(const float*)d_in[18];
  const float* wc2  =(const float*)d_in[19];
  const float* ws2  =(const float*)d_in[20];
  const float* bng2 =(const float*)d_in[21];
  const float* bnb2 =(const float*)d_in[22];
  const float* ng2  =(const float*)d_in[23];
  const float* nb2  =(const float*)d_in[24];
  const float* fc1w =(const float*)d_in[25];
  const float* fc1b =(const float*)d_in[26];
  const float* fc2w =(const float*)d_in[27];
  const float* fc2b =(const float*)d_in[28];
  float* outp=(float*)d_out;

  char* base=(char*)d_ws;
  size_t off=0;
  auto alloc=[&](size_t nbytes)->void*{
    void* p=base+off; off=(off+nbytes+255)&~(size_t)255; return p; };

  float* psum0 =(float*)alloc((size_t)12*131072);
  float* bc    =(float*)alloc(8192);
  float* wt_wc0=(float*)alloc((size_t)36*64*4);
  u16*   bws0  =(u16*)alloc((size_t)3*16384*2);
  u16*   bwc1  =(u16*)alloc((size_t)32768*2);
  u16*   bws1  =(u16*)alloc((size_t)3*65536*2);
  u16*   bwc2  =(u16*)alloc((size_t)131072*2);
  u16*   bws2  =(u16*)alloc((size_t)3*262144*2);
  float* xT    =(float*)alloc((size_t)8*12000*9*4);
  float* B0    =(float*)alloc((size_t)49152000);
  float* B1    =(float*)alloc((size_t)49152000);
  float* B2    =(float*)alloc((size_t)49152000);
  if (off>ws_size) return;

  auto PS=[&](int i){ return psum0+(size_t)i*32768; };

  hipMemsetAsync(psum0,0,(size_t)12*131072+8192,stream);

  { int n=8*9*12000; transpose_in_kernel<<<(n+255)/256,256,0,stream>>>(x,xT,12000); }
  { int n=36*64; transpose_w_kernel<<<(n+255)/256,256,0,stream>>>(wc0,wt_wc0,36,64); }
  auto cv=[&](const float* w,u16* o,int n){
    cvt_bf16_kernel<<<(n+255)/256,256,0,stream>>>(w,o,n); };
  cv(ws0,bws0,3*16384);
  cv(wc1,bwc1,32768);
  cv(ws1,bws1,3*65536);
  cv(wc2,bwc2,131072);
  cv(ws2,bws2,3*262144);

  // -------- stage 0: F=12000, 9 -> 64 --------
  {
    const int F=12000; const float invN=1.f/(8.f*F);
    dim3 grid((F+TILE_F-1)/TILE_F, 8);
    conv_kernel<9,64,false,true><<<grid,256,0,stream>>>(xT,nbr0,wt_wc0,nullptr,nullptr,B0,PS(0),F);
    launch_mconv<64,64,32,2,true,true ,false>(B0,nbr0,bws0,        PS(0),bng0,     bnb0,     nullptr,B1,PS(1),F,invN,stream);
    launch_mconv<64,64,32,2,true,true ,false>(B1,nbr0,bws0+16384,  PS(1),bng0+64,  bnb0+64,  nullptr,B2,PS(2),F,invN,stream);
    // 4th conv: fused residual relu(y + B0) + stats for the outer BN (PS(3))
    launch_mconv<64,64,32,2,true,true ,true >(B2,nbr0,bws0+32768,  PS(2),bng0+128, bnb0+128, B0,     B1,PS(3),F,invN,stream);
    int n4p=8*9000*16; int gp=(n4p+255)/256; if (gp>2048) gp=2048;
    pool_kernel<<<gp,256,0,stream>>>(B1,pool0,PS(3),ng0,nb0,B2,16,F,9000,n4p,invN);
  }
  // -------- stage 1: F=9000, 64 -> 128 --------
  {
    const int F=9000; const float invN=1.f/(8.f*F);
    launch_mconv<64,128,64,1,false,true ,false>(B2,nbr1,bwc1,         nullptr,nullptr,  nullptr,  nullptr,B0,PS(4),F,invN,stream);
    launch_mconv<128,128,64,1,true,true ,false>(B0,nbr1,bws1,         PS(4),bng1,      bnb1,     nullptr,B1,PS(5),F,invN,stream);
    launch_mconv<128,128,64,1,true,true ,false>(B1,nbr1,bws1+65536,   PS(5),bng1+128,  bnb1+128, nullptr,B2,PS(6),F,invN,stream);
    launch_mconv<128,128,64,1,true,true ,true >(B2,nbr1,bws1+131072,  PS(6),bng1+256,  bnb1+256, B0,     B1,PS(7),F,invN,stream);
    int n4p=8*6000*32; int gp=(n4p+255)/256; if (gp>2048) gp=2048;
    pool_kernel<<<gp,256,0,stream>>>(B1,pool1,PS(7),ng1,nb1,B0,32,F,6000,n4p,invN);
  }
  // -------- stage 2: F=6000, 128 -> 256 --------
  {
    const int F=6000; const float invN=1.f/(8.f*F);
    launch_mconv<128,256,64,1,false,true ,false>(B0,nbr2,bwc2,         nullptr,nullptr,  nullptr,  nullptr,B1,PS(8),F,invN,stream);
    launch_mconv<256,256,64,1,true,true ,false>(B1,nbr2,bws2,         PS(8), bng2,     bnb2,     nullptr,B2,PS(9),F,invN,stream);
    launch_mconv<256,256,64,1,true,true ,false>(B2,nbr2,bws2+262144,  PS(9), bng2+256, bnb2+256, nullptr,B0,PS(10),F,invN,stream);
    launch_mconv<256,256,64,1,true,true ,true >(B0,nbr2,bws2+524288,  PS(10),bng2+512, bnb2+512, B1,     B2,PS(11),F,invN,stream);
    int n4p=8*4000*64; int gp=(n4p+255)/256; if (gp>2048) gp=2048;
    pool_kernel<<<gp,256,0,stream>>>(B2,pool2,PS(11),ng2,nb2,B0,64,F,4000,n4p,invN);
    colsum_kernel<<<dim3(16,8),256,0,stream>>>(B0,bc,4000,250);
  }
  head_kernel<<<1,256,0,stream>>>(bc,fc1w,fc1b,fc2w,fc2b,outp,1.f/4000.f);
}